// Round 4
// baseline (259.816 us; speedup 1.0000x reference)
//
#include <hip/hip_runtime.h>
#include <hip/hip_bf16.h>

// MHA forward. Device dtypes: float32 inputs (q,k,v,weights), int32 mask, FLOAT32 output
// (reference returns f32; bf16-grade threshold permits bf16 internal pipeline).
// B=2, S=2048, D_MODEL=1024, H=16, DK=64.
// Pipeline: [QKV proj GEMM (fused, z=3), f32->bf16 inline] -> [flash attention bf16]
//           -> [O proj GEMM, f32 out].

typedef short short8 __attribute__((ext_vector_type(8)));
typedef float f32x4 __attribute__((ext_vector_type(4)));

#define D_MODEL 1024
#define SEQ     2048
#define NBATCH  2
#define NHEAD   16
#define DKD     64
#define HSTR    (SEQ * DKD)     // 131072 elems per (b,h) plane

#define MFMA16(a, b, c) __builtin_amdgcn_mfma_f32_16x16x32_bf16((a), (b), (c), 0, 0, 0)

// round-to-nearest-even f32 -> bf16 bits
__device__ __forceinline__ ushort f2bf(float f) {
    union { float f; unsigned u; } a; a.f = f;
    unsigned r = a.u + 0x7fffu + ((a.u >> 16) & 1u);
    return (ushort)(r >> 16);
}

// Read one MFMA operand fragment (8 bf16 = 16B) from a row-major [rows][64] LDS tile
// stored with the XOR swizzle: phys_byte = row*128 + ((col*2) ^ ((row&7)<<4)).
__device__ __forceinline__ short8 lds_frag(const ushort* base, int row, int c0) {
    int cb = (c0 * 2) ^ ((row & 7) << 4);
    return *(const short8*)((const char*)base + row * 128 + cb);
}

// ---------------------------------------------------------------------------
// GEMM: C[M=4096][N=1024] = A[4096][1024] * W[1024(out)][1024(in)]^T  (NT form)
// A_BF16=0: A is f32 (model inputs), converted to bf16 during staging.
// A_BF16=1: A is bf16 (workspace). W always f32.
// LAYOUT 0: write bf16 head-split out[(b*16+h)*HSTR + s*64 + dk]
// LAYOUT 1: write f32 plain      out[m*1024 + n]
// Block: 256 thr (4 waves, 2x2), tile 128x128, BK=64.
// ---------------------------------------------------------------------------
template<int LAYOUT, int A_BF16>
__global__ __launch_bounds__(256, 2) void gemm_nt(
    const void* __restrict__ A0, const void* __restrict__ A1, const void* __restrict__ A2,
    const float* __restrict__ W0, const float* __restrict__ W1, const float* __restrict__ W2,
    void* __restrict__ O0, void* __restrict__ O1, void* __restrict__ O2)
{
    const int z = blockIdx.z;
    const void*  A = (z == 0) ? A0 : ((z == 1) ? A1 : A2);
    const float* W = (z == 0) ? W0 : ((z == 1) ? W1 : W2);
    void* O        = (z == 0) ? O0 : ((z == 1) ? O1 : O2);

    const int bm = blockIdx.x * 128;
    const int bn = blockIdx.y * 128;
    const int tid = threadIdx.x;
    const int w = tid >> 6, l = tid & 63;
    const int wr = w >> 1, wc = w & 1;

    __shared__ ushort sm[16384];   // A tile [0,8192) as [128][64]; B tile [8192,16384)

    f32x4 acc[4][4] = {};

    for (int t = 0; t < 16; ++t) {
        __syncthreads();
        #pragma unroll
        for (int i = 0; i < 4; ++i) {
            int flat = i * 256 + tid;            // 0..1023
            int row  = flat >> 3;                // 0..127
            int c8   = (flat & 7) << 3;          // logical col base (elems)
            int cb   = (c8 * 2) ^ ((row & 7) << 4);
            short8 av;
            if (A_BF16) {
                av = *(const short8*)((const ushort*)A + (size_t)(bm + row) * 1024 + t * 64 + c8);
            } else {
                const float* ap = (const float*)A + (size_t)(bm + row) * 1024 + t * 64 + c8;
                f32x4 x0 = *(const f32x4*)ap, x1 = *(const f32x4*)(ap + 4);
                #pragma unroll
                for (int u = 0; u < 4; ++u) { av[u] = (short)f2bf(x0[u]); av[4 + u] = (short)f2bf(x1[u]); }
            }
            *(short8*)((char*)sm + row * 128 + cb) = av;

            const float* wp = W + (size_t)(bn + row) * 1024 + t * 64 + c8;
            f32x4 y0 = *(const f32x4*)wp, y1 = *(const f32x4*)(wp + 4);
            short8 wv;
            #pragma unroll
            for (int u = 0; u < 4; ++u) { wv[u] = (short)f2bf(y0[u]); wv[4 + u] = (short)f2bf(y1[u]); }
            *(short8*)((char*)(sm + 8192) + row * 128 + cb) = wv;
        }
        __syncthreads();

        #pragma unroll
        for (int kk = 0; kk < 2; ++kk) {
            const int c0 = kk * 32 + ((l >> 4) << 3);
            short8 af[4], bf[4];
            #pragma unroll
            for (int mi = 0; mi < 4; ++mi)
                af[mi] = lds_frag(sm, wr * 64 + mi * 16 + (l & 15), c0);
            #pragma unroll
            for (int ni = 0; ni < 4; ++ni)
                bf[ni] = lds_frag(sm + 8192, wc * 64 + ni * 16 + (l & 15), c0);
            #pragma unroll
            for (int mi = 0; mi < 4; ++mi)
                #pragma unroll
                for (int ni = 0; ni < 4; ++ni)
                    acc[mi][ni] = MFMA16(af[mi], bf[ni], acc[mi][ni]);
        }
    }

    // epilogue: C/D layout col=lane&15, row=(lane>>4)*4+reg
    #pragma unroll
    for (int mi = 0; mi < 4; ++mi) {
        #pragma unroll
        for (int ni = 0; ni < 4; ++ni) {
            #pragma unroll
            for (int j = 0; j < 4; ++j) {
                int m = bm + wr * 64 + mi * 16 + ((l >> 4) << 2) + j;
                int n = bn + wc * 64 + ni * 16 + (l & 15);
                if (LAYOUT == 0) {
                    int b = m >> 11, s = m & 2047, h = n >> 6, dk = n & 63;
                    ((ushort*)O)[(size_t)(b * NHEAD + h) * HSTR + s * DKD + dk] = f2bf(acc[mi][ni][j]);
                } else {
                    ((float*)O)[(size_t)m * 1024 + n] = acc[mi][ni][j];
                }
            }
        }
    }
}

// ---------------------------------------------------------------------------
// Flash attention over head-split bf16 Q/K/V [b*16+h][s][dk].
// Block: 256 thr (4 waves). 128 Q-rows per block (32/wave), KV tiles of 64.
// Writes context bf16 in [b][s][h*64+dk] layout.
// ---------------------------------------------------------------------------
__global__ __launch_bounds__(256, 2) void attn_fwd(
    const ushort* __restrict__ Q, const ushort* __restrict__ K, const ushort* __restrict__ V,
    const int* __restrict__ mask, ushort* __restrict__ ctx)
{
    const int tid = threadIdx.x;
    const int w = tid >> 6, l = tid & 63;
    const int q0 = blockIdx.x * 128;
    const int bh = blockIdx.y;
    const int b  = bh >> 4;
    const int h  = bh & 15;

    __shared__ ushort sm[16384];   // K [0,4096) as [64][64]; Vt [4096,8192) as [64dk][64kv]; P [8192,16384): per-wave [32][64]
    __shared__ float  smf[SEQ];    // additive mask for this batch row

    const ushort* Qh = Q + (size_t)bh * HSTR;
    const ushort* Kh = K + (size_t)bh * HSTR;
    const ushort* Vh = V + (size_t)bh * HSTR;

    for (int i = tid; i < SEQ; i += 256)
        smf[i] = (mask[b * SEQ + i] == 0) ? -1e9f : 0.0f;

    // Q fragments held in registers (A operand of QK^T)
    short8 qf[2][2];
    #pragma unroll
    for (int mi = 0; mi < 2; ++mi)
        #pragma unroll
        for (int kk = 0; kk < 2; ++kk)
            qf[mi][kk] = *(const short8*)(Qh + (size_t)(q0 + w * 32 + mi * 16 + (l & 15)) * DKD
                                          + kk * 32 + ((l >> 4) << 3));

    f32x4 acc_o[2][4] = {};
    float m_run[2][4], l_run[2][4];
    #pragma unroll
    for (int mi = 0; mi < 2; ++mi)
        #pragma unroll
        for (int j = 0; j < 4; ++j) { m_run[mi][j] = -INFINITY; l_run[mi][j] = 0.0f; }

    ushort* Pw = sm + 8192 + w * 2048;     // per-wave P tile [32][64]

    #pragma unroll 1
    for (int kt = 0; kt < 32; ++kt) {
        __syncthreads();   // previous tile fully consumed before restage
        // --- stage K tile [64][64], swizzled reg-staged writes
        #pragma unroll
        for (int i = 0; i < 2; ++i) {
            int flat = i * 256 + tid;            // 0..511
            int row  = flat >> 3;                // 0..63
            int c8   = (flat & 7) << 3;
            int cb   = (c8 * 2) ^ ((row & 7) << 4);
            short8 kv8 = *(const short8*)(Kh + (size_t)(kt * 64 + row) * DKD + c8);
            *(short8*)((char*)sm + row * 128 + cb) = kv8;
        }
        // --- stage V transposed: Vt[dk][kv], coalesced ushort gathers + swizzled b128 write
        #pragma unroll
        for (int it = 0; it < 2; ++it) {
            int kv0 = w * 8 + it * 32;
            short8 vv;
            #pragma unroll
            for (int ii = 0; ii < 8; ++ii)
                vv[ii] = (short)Vh[(size_t)(kt * 64 + kv0 + ii) * DKD + l];
            int cb = (kv0 * 2) ^ ((l & 7) << 4);
            *(short8*)((char*)(sm + 4096) + l * 128 + cb) = vv;
        }
        __syncthreads();

        // --- scores = Q K^T
        f32x4 s4[2][4] = {};
        #pragma unroll
        for (int kk = 0; kk < 2; ++kk) {
            const int c0 = kk * 32 + ((l >> 4) << 3);
            short8 kf[4];
            #pragma unroll
            for (int ni = 0; ni < 4; ++ni)
                kf[ni] = lds_frag(sm, ni * 16 + (l & 15), c0);
            #pragma unroll
            for (int mi = 0; mi < 2; ++mi)
                #pragma unroll
                for (int ni = 0; ni < 4; ++ni)
                    s4[mi][ni] = MFMA16(qf[mi][kk], kf[ni], s4[mi][ni]);
        }

        // --- scale + mask
        #pragma unroll
        for (int ni = 0; ni < 4; ++ni) {
            float madd = smf[kt * 64 + ni * 16 + (l & 15)];
            #pragma unroll
            for (int mi = 0; mi < 2; ++mi)
                #pragma unroll
                for (int j = 0; j < 4; ++j)
                    s4[mi][ni][j] = s4[mi][ni][j] * 0.125f + madd;
        }

        // --- online softmax (row = mi*16 + (l>>4)*4 + j, spread across lanes l&15)
        #pragma unroll
        for (int mi = 0; mi < 2; ++mi) {
            #pragma unroll
            for (int j = 0; j < 4; ++j) {
                float tmax = fmaxf(fmaxf(s4[mi][0][j], s4[mi][1][j]),
                                   fmaxf(s4[mi][2][j], s4[mi][3][j]));
                #pragma unroll
                for (int d = 1; d < 16; d <<= 1) tmax = fmaxf(tmax, __shfl_xor(tmax, d));
                float mnew = fmaxf(m_run[mi][j], tmax);
                float c = __expf(m_run[mi][j] - mnew);
                float rsum = 0.0f;
                #pragma unroll
                for (int ni = 0; ni < 4; ++ni) {
                    float p = __expf(s4[mi][ni][j] - mnew);
                    s4[mi][ni][j] = p;
                    rsum += p;
                }
                #pragma unroll
                for (int d = 1; d < 16; d <<= 1) rsum += __shfl_xor(rsum, d);
                l_run[mi][j] = l_run[mi][j] * c + rsum;
                m_run[mi][j] = mnew;
                #pragma unroll
                for (int ni = 0; ni < 4; ++ni) acc_o[mi][ni][j] *= c;
            }
        }

        // --- P (bf16) -> per-wave LDS (swizzled), then PV MFMAs
        #pragma unroll
        for (int mi = 0; mi < 2; ++mi)
            #pragma unroll
            for (int ni = 0; ni < 4; ++ni)
                #pragma unroll
                for (int j = 0; j < 4; ++j) {
                    int row = mi * 16 + ((l >> 4) << 2) + j;
                    int cb  = ((ni * 16 + (l & 15)) * 2) ^ ((row & 7) << 4);
                    *(ushort*)((char*)Pw + row * 128 + cb) = f2bf(s4[mi][ni][j]);
                }

        #pragma unroll
        for (int kk = 0; kk < 2; ++kk) {
            const int c0 = kk * 32 + ((l >> 4) << 3);
            short8 pa[2], vf[4];
            #pragma unroll
            for (int mi = 0; mi < 2; ++mi)
                pa[mi] = lds_frag(Pw, mi * 16 + (l & 15), c0);
            #pragma unroll
            for (int ni = 0; ni < 4; ++ni)
                vf[ni] = lds_frag(sm + 4096, ni * 16 + (l & 15), c0);
            #pragma unroll
            for (int mi = 0; mi < 2; ++mi)
                #pragma unroll
                for (int ni = 0; ni < 4; ++ni)
                    acc_o[mi][ni] = MFMA16(pa[mi], vf[ni], acc_o[mi][ni]);
        }
    }

    // --- epilogue: normalize, write context [b][s][h*64+dk]
    #pragma unroll
    for (int mi = 0; mi < 2; ++mi) {
        #pragma unroll
        for (int j = 0; j < 4; ++j) {
            float inv = 1.0f / l_run[mi][j];
            int qg = q0 + w * 32 + mi * 16 + ((l >> 4) << 2) + j;
            #pragma unroll
            for (int ni = 0; ni < 4; ++ni) {
                int dk = ni * 16 + (l & 15);
                ctx[(size_t)(b * SEQ + qg) * D_MODEL + h * DKD + dk] = f2bf(acc_o[mi][ni][j] * inv);
            }
        }
    }
}

// Diagnostic sentinel: if ws is too small, report its size in-band via absmax.
__global__ void ws_sentinel(float* __restrict__ out, int n, float code) {
    int i = blockIdx.x * blockDim.x + threadIdx.x;
    if (i < n) out[i] = (i == 0) ? code : 0.0f;
}

// ---------------------------------------------------------------------------
extern "C" void kernel_launch(void* const* d_in, const int* in_sizes, int n_in,
                              void* d_out, int out_size, void* d_ws, size_t ws_size,
                              hipStream_t stream) {
    const float* q    = (const float*)d_in[0];
    const float* k    = (const float*)d_in[1];
    const float* v    = (const float*)d_in[2];
    const int*   mask = (const int*)d_in[3];
    const float* wq   = (const float*)d_in[4];
    const float* wk   = (const float*)d_in[5];
    const float* wv   = (const float*)d_in[6];
    const float* wo   = (const float*)d_in[7];
    float* out = (float*)d_out;

    if (ws_size < (size_t)33554432) {   // need 32 MB: report ws_MB in-band and bail
        float code = 100.0f + (float)(ws_size >> 20);
        ws_sentinel<<<(out_size + 255) / 256, 256, 0, stream>>>(out, out_size, code);
        return;
    }

    ushort* ws = (ushort*)d_ws;
    ushort* Qb = ws;                       // [b,h,s,dk] bf16 (8 MB)
    ushort* Kb = ws + 4194304;
    ushort* Vb = ws + 8388608;
    ushort* Cb = ws + 12582912;            // context [b,s,d] bf16 (8 MB)

    dim3 blk(256, 1, 1);
    gemm_nt<0, 0><<<dim3(32, 8, 3), blk, 0, stream>>>(q, k, v, wq, wk, wv, Qb, Kb, Vb);
    attn_fwd<<<dim3(16, 32, 1), blk, 0, stream>>>(Qb, Kb, Vb, mask, Cb);
    gemm_nt<1, 1><<<dim3(32, 8, 1), blk, 0, stream>>>(Cb, Cb, Cb, wo, wo, wo, out, out, out);
}

// Round 5
// 259.342 us; speedup vs baseline: 1.0018x; 1.0018x over previous
//
#include <hip/hip_runtime.h>
#include <hip/hip_bf16.h>

// MHA forward. f32 inputs (+int32 mask), f32 output; bf16 internal pipeline.
// B=2, S=2048, D_MODEL=1024, H=16, DK=64.
// [QKV proj GEMM z=3 (Q scaled 1/8; V written transposed)] -> [flash attn] -> [O proj].

typedef short short8 __attribute__((ext_vector_type(8)));
typedef float f32x4 __attribute__((ext_vector_type(4)));

#define D_MODEL 1024
#define SEQ     2048
#define NBATCH  2
#define NHEAD   16
#define DKD     64
#define HSTR    (SEQ * DKD)     // 131072 elems per (b,h) plane

#define MFMA16(a, b, c) __builtin_amdgcn_mfma_f32_16x16x32_bf16((a), (b), (c), 0, 0, 0)

__device__ __forceinline__ ushort f2bf(float f) {
    union { float f; unsigned u; } a; a.f = f;
    unsigned r = a.u + 0x7fffu + ((a.u >> 16) & 1u);
    return (ushort)(r >> 16);
}

// frag read from swizzled tile, row byte-stride 128 (64-col tiles)
__device__ __forceinline__ short8 frag128(const ushort* base, int row, int c0) {
    int cb = (c0 * 2) ^ ((row & 7) << 4);
    return *(const short8*)((const char*)base + row * 128 + cb);
}
// frag read from swizzled tile, row byte-stride 256 (128-col tiles)
__device__ __forceinline__ short8 frag256(const ushort* base, int row, int c0) {
    int cb = (c0 * 2) ^ ((row & 7) << 4);
    return *(const short8*)((const char*)base + row * 256 + cb);
}

// ---------------------------------------------------------------------------
// GEMM: C[4096][1024] = A[4096][1024] * W[1024][1024]^T (NT).
// LAYOUT 0 (QKV): z==0 -> head-split bf16, scaled 0.125 (Q); z==1 -> head-split (K);
//                 z==2 -> transposed bf16 [bh][dk][s] (V).
// LAYOUT 1: plain f32 out[m*1024+n] (O-proj).
// ---------------------------------------------------------------------------
template<int LAYOUT, int A_BF16>
__global__ __launch_bounds__(256, 2) void gemm_nt(
    const void* __restrict__ A0, const void* __restrict__ A1, const void* __restrict__ A2,
    const float* __restrict__ W0, const float* __restrict__ W1, const float* __restrict__ W2,
    void* __restrict__ O0, void* __restrict__ O1, void* __restrict__ O2)
{
    const int z = blockIdx.z;
    const void*  A = (z == 0) ? A0 : ((z == 1) ? A1 : A2);
    const float* W = (z == 0) ? W0 : ((z == 1) ? W1 : W2);
    void* O        = (z == 0) ? O0 : ((z == 1) ? O1 : O2);

    const int bm = blockIdx.x * 128;
    const int bn = blockIdx.y * 128;
    const int tid = threadIdx.x;
    const int w = tid >> 6, l = tid & 63;
    const int wr = w >> 1, wc = w & 1;

    __shared__ ushort sm[16384];   // A tile [0,8192) as [128][64]; B tile [8192,16384)

    f32x4 acc[4][4] = {};

    for (int t = 0; t < 16; ++t) {
        __syncthreads();
        #pragma unroll
        for (int i = 0; i < 4; ++i) {
            int flat = i * 256 + tid;            // 0..1023
            int row  = flat >> 3;                // 0..127
            int c8   = (flat & 7) << 3;
            int cb   = (c8 * 2) ^ ((row & 7) << 4);
            short8 av;
            if (A_BF16) {
                av = *(const short8*)((const ushort*)A + (size_t)(bm + row) * 1024 + t * 64 + c8);
            } else {
                const float* ap = (const float*)A + (size_t)(bm + row) * 1024 + t * 64 + c8;
                f32x4 x0 = *(const f32x4*)ap, x1 = *(const f32x4*)(ap + 4);
                #pragma unroll
                for (int u = 0; u < 4; ++u) { av[u] = (short)f2bf(x0[u]); av[4 + u] = (short)f2bf(x1[u]); }
            }
            *(short8*)((char*)sm + row * 128 + cb) = av;

            const float* wp = W + (size_t)(bn + row) * 1024 + t * 64 + c8;
            f32x4 y0 = *(const f32x4*)wp, y1 = *(const f32x4*)(wp + 4);
            short8 wv;
            #pragma unroll
            for (int u = 0; u < 4; ++u) { wv[u] = (short)f2bf(y0[u]); wv[4 + u] = (short)f2bf(y1[u]); }
            *(short8*)((char*)(sm + 8192) + row * 128 + cb) = wv;
        }
        __syncthreads();

        #pragma unroll
        for (int kk = 0; kk < 2; ++kk) {
            const int c0 = kk * 32 + ((l >> 4) << 3);
            short8 af[4], bf[4];
            #pragma unroll
            for (int mi = 0; mi < 4; ++mi)
                af[mi] = frag128(sm, wr * 64 + mi * 16 + (l & 15), c0);
            #pragma unroll
            for (int ni = 0; ni < 4; ++ni)
                bf[ni] = frag128(sm + 8192, wc * 64 + ni * 16 + (l & 15), c0);
            #pragma unroll
            for (int mi = 0; mi < 4; ++mi)
                #pragma unroll
                for (int ni = 0; ni < 4; ++ni)
                    acc[mi][ni] = MFMA16(af[mi], bf[ni], acc[mi][ni]);
        }
    }

    const float sc = (LAYOUT == 0 && z == 0) ? 0.125f : 1.0f;
    #pragma unroll
    for (int mi = 0; mi < 4; ++mi) {
        #pragma unroll
        for (int ni = 0; ni < 4; ++ni) {
            #pragma unroll
            for (int j = 0; j < 4; ++j) {
                int m = bm + wr * 64 + mi * 16 + ((l >> 4) << 2) + j;
                int n = bn + wc * 64 + ni * 16 + (l & 15);
                if (LAYOUT == 0) {
                    int b = m >> 11, s = m & 2047, h = n >> 6, dk = n & 63;
                    if (z == 2)   // V: transposed [bh][dk][s]
                        ((ushort*)O)[(size_t)(b * NHEAD + h) * HSTR + dk * SEQ + s] = f2bf(acc[mi][ni][j]);
                    else          // Q (scaled) / K: head-split [bh][s][dk]
                        ((ushort*)O)[(size_t)(b * NHEAD + h) * HSTR + s * DKD + dk] = f2bf(acc[mi][ni][j] * sc);
                } else {
                    ((float*)O)[(size_t)m * 1024 + n] = acc[mi][ni][j];
                }
            }
        }
    }
}

// ---------------------------------------------------------------------------
// Flash attention. Q,K head-split [bh][s][dk]; V transposed [bh][dk][s]. All bf16.
// Grid: 1024 blocks (XCD-chunked), 256 thr = 4 waves; QBLK=64 (16 q-rows/wave),
// KVBLK=128, 16 tiles. LDS 32KB: K[128][64] (aliased by per-wave P[16][128]
// after QK^T barrier) + Vt[64][128]. Async reg-staging, setprio, defer-max.
// ---------------------------------------------------------------------------
__global__ __launch_bounds__(256, 2) void attn_fwd(
    const ushort* __restrict__ Q, const ushort* __restrict__ K, const ushort* __restrict__ Vt,
    const int* __restrict__ mask, ushort* __restrict__ ctx)
{
    const int tid = threadIdx.x;
    const int w = tid >> 6, l = tid & 63;
    // XCD-chunked swizzle: 1024 blocks, 8 XCDs, 128/chunk -> 4 bh per XCD.
    const int id  = blockIdx.x;
    const int nid = (id & 7) * 128 + (id >> 3);
    const int bh  = nid >> 5;
    const int q0  = (nid & 31) * 64;
    const int b   = bh >> 4, h = bh & 15;

    __shared__ ushort sm[16384];   // [0,8192): K [128][64] swz / P per-wave [16][128] swz
                                   // [8192,16384): Vt [64][128] swz

    const ushort* Qh = Q  + (size_t)bh * HSTR;
    const ushort* Kh = K  + (size_t)bh * HSTR;
    const ushort* Vh = Vt + (size_t)bh * HSTR;     // [dk][s]

    // Q fragments (A operand): rows q0 + w*16 + (l&15), k-slices kk*32+(l>>4)*8
    short8 qf[2];
    #pragma unroll
    for (int kk = 0; kk < 2; ++kk)
        qf[kk] = *(const short8*)(Qh + (size_t)(q0 + w * 16 + (l & 15)) * DKD
                                  + kk * 32 + ((l >> 4) << 3));

    f32x4 acc_o[4] = {};
    float m_run[4], l_run[4];
    #pragma unroll
    for (int j = 0; j < 4; ++j) { m_run[j] = -INFINITY; l_run[j] = 0.0f; }

    short8 kreg[4], vreg[4];
    const int kflat_r = tid >> 3,          kflat_c = (tid & 7) << 3;     // K: per-i row += 32
    const int vflat_r = tid >> 4,          vflat_c = (tid & 15) << 3;    // Vt: per-i row += 16

    #define LOADT(kt_) {                                                              \
        _Pragma("unroll")                                                             \
        for (int i = 0; i < 4; ++i)                                                   \
            kreg[i] = *(const short8*)(Kh + (size_t)((kt_) * 128 + i * 32 + kflat_r) * DKD + kflat_c); \
        _Pragma("unroll")                                                             \
        for (int i = 0; i < 4; ++i)                                                   \
            vreg[i] = *(const short8*)(Vh + (size_t)(i * 16 + vflat_r) * SEQ + (kt_) * 128 + vflat_c); }

    #define WRITET() {                                                                \
        _Pragma("unroll")                                                             \
        for (int i = 0; i < 4; ++i) {                                                 \
            int r = i * 32 + kflat_r;                                                 \
            *(short8*)((char*)sm + r * 128 + (((kflat_c * 2)) ^ ((r & 7) << 4))) = kreg[i]; } \
        _Pragma("unroll")                                                             \
        for (int i = 0; i < 4; ++i) {                                                 \
            int r = i * 16 + vflat_r;                                                 \
            *(short8*)((char*)(sm + 8192) + r * 256 + (((vflat_c * 2)) ^ ((r & 7) << 4))) = vreg[i]; } }

    LOADT(0); WRITET();
    __syncthreads();                               // tile 0 staged

    ushort* Pw = sm + w * 2048;                    // per-wave P [16][128], aliases K region

    #pragma unroll 1
    for (int kt = 0; kt < 16; ++kt) {
        if (kt < 15) LOADT(kt + 1);                // async: issue early, write after bar C
        float madd[8];
        #pragma unroll
        for (int ni = 0; ni < 8; ++ni)
            madd[ni] = (mask[b * SEQ + kt * 128 + ni * 16 + (l & 15)] == 0) ? -1e9f : 0.0f;

        // --- QK^T (scale already folded into Q)
        f32x4 s4[8] = {};
        __builtin_amdgcn_s_setprio(1);
        #pragma unroll
        for (int kk = 0; kk < 2; ++kk) {
            const int c0 = kk * 32 + ((l >> 4) << 3);
            #pragma unroll
            for (int ni = 0; ni < 8; ++ni) {
                short8 kf = frag128(sm, ni * 16 + (l & 15), c0);
                s4[ni] = MFMA16(qf[kk], kf, s4[ni]);
            }
        }
        __builtin_amdgcn_s_setprio(0);
        __syncthreads();                           // bar B: K reads done -> K region becomes P

        // --- mask + online softmax (rows j, cols across lanes l&15)
        #pragma unroll
        for (int ni = 0; ni < 8; ++ni)
            #pragma unroll
            for (int j = 0; j < 4; ++j) s4[ni][j] += madd[ni];

        float tmax[4]; bool ng = true;
        #pragma unroll
        for (int j = 0; j < 4; ++j) {
            float t = s4[0][j];
            #pragma unroll
            for (int ni = 1; ni < 8; ++ni) t = fmaxf(t, s4[ni][j]);
            #pragma unroll
            for (int d = 1; d < 16; d <<= 1) t = fmaxf(t, __shfl_xor(t, d));
            tmax[j] = t;
            ng = ng && (t <= m_run[j]);
        }
        const bool nogrow = __all(ng);             // defer-max (exact: skip c==1 work)

        #pragma unroll
        for (int j = 0; j < 4; ++j) {
            float mnew = nogrow ? m_run[j] : fmaxf(m_run[j], tmax[j]);
            float rsum = 0.0f;
            #pragma unroll
            for (int ni = 0; ni < 8; ++ni) {
                float p = __expf(s4[ni][j] - mnew);
                s4[ni][j] = p;
                rsum += p;
            }
            #pragma unroll
            for (int d = 1; d < 16; d <<= 1) rsum += __shfl_xor(rsum, d);
            if (nogrow) {
                l_run[j] += rsum;
            } else {
                float c = __expf(m_run[j] - mnew);
                l_run[j] = l_run[j] * c + rsum;
                m_run[j] = mnew;
                #pragma unroll
                for (int ni = 0; ni < 4; ++ni) acc_o[ni][j] *= c;
            }
        }

        // --- P (bf16) -> per-wave swizzled LDS [16][128]
        #pragma unroll
        for (int ni = 0; ni < 8; ++ni)
            #pragma unroll
            for (int j = 0; j < 4; ++j) {
                int row = ((l >> 4) << 2) + j;
                int cb  = ((ni * 16 + (l & 15)) * 2) ^ ((row & 7) << 4);
                *(ushort*)((char*)Pw + row * 256 + cb) = f2bf(s4[ni][j]);
            }

        // --- PV: acc_o[dk-tile] += P[16][128] * V[128][dk]
        __builtin_amdgcn_s_setprio(1);
        #pragma unroll
        for (int kk = 0; kk < 4; ++kk) {
            const int c0 = kk * 32 + ((l >> 4) << 3);
            short8 pa = frag256(Pw, l & 15, c0);
            #pragma unroll
            for (int ni = 0; ni < 4; ++ni) {
                short8 vf = frag256(sm + 8192, ni * 16 + (l & 15), c0);
                acc_o[ni] = MFMA16(pa, vf, acc_o[ni]);
            }
        }
        __builtin_amdgcn_s_setprio(0);
        __syncthreads();                           // bar C: P/Vt reads done
        if (kt < 15) {
            WRITET();                              // stage tile kt+1
            __syncthreads();                       // bar A: tile ready
        }
    }

    // --- epilogue: normalize, write context [b][s][h*64+dk]
    #pragma unroll
    for (int j = 0; j < 4; ++j) {
        float inv = 1.0f / l_run[j];
        int qg = q0 + w * 16 + ((l >> 4) << 2) + j;
        #pragma unroll
        for (int ni = 0; ni < 4; ++ni) {
            int dk = ni * 16 + (l & 15);
            ctx[(size_t)(b * SEQ + qg) * D_MODEL + h * DKD + dk] = f2bf(acc_o[ni][j] * inv);
        }
    }
    #undef LOADT
    #undef WRITET
}

// Diagnostic sentinel: if ws is too small, report its size in-band via absmax.
__global__ void ws_sentinel(float* __restrict__ out, int n, float code) {
    int i = blockIdx.x * blockDim.x + threadIdx.x;
    if (i < n) out[i] = (i == 0) ? code : 0.0f;
}

// ---------------------------------------------------------------------------
extern "C" void kernel_launch(void* const* d_in, const int* in_sizes, int n_in,
                              void* d_out, int out_size, void* d_ws, size_t ws_size,
                              hipStream_t stream) {
    const float* q    = (const float*)d_in[0];
    const float* k    = (const float*)d_in[1];
    const float* v    = (const float*)d_in[2];
    const int*   mask = (const int*)d_in[3];
    const float* wq   = (const float*)d_in[4];
    const float* wk   = (const float*)d_in[5];
    const float* wv   = (const float*)d_in[6];
    const float* wo   = (const float*)d_in[7];
    float* out = (float*)d_out;

    if (ws_size < (size_t)33554432) {
        float code = 100.0f + (float)(ws_size >> 20);
        ws_sentinel<<<(out_size + 255) / 256, 256, 0, stream>>>(out, out_size, code);
        return;
    }

    ushort* ws = (ushort*)d_ws;
    ushort* Qb = ws;                       // [bh][s][dk] bf16 (scaled 1/8)
    ushort* Kb = ws + 4194304;             // [bh][s][dk]
    ushort* Vb = ws + 8388608;             // [bh][dk][s]  (transposed)
    ushort* Cb = ws + 12582912;            // context [b,s,d] bf16

    dim3 blk(256, 1, 1);
    gemm_nt<0, 0><<<dim3(32, 8, 3), blk, 0, stream>>>(q, k, v, wq, wk, wv, Qb, Kb, Vb);
    attn_fwd<<<dim3(1024, 1, 1), blk, 0, stream>>>(Qb, Kb, Vb, mask, Cb);
    gemm_nt<1, 1><<<dim3(32, 8, 1), blk, 0, stream>>>(Cb, Cb, Cb, wo, wo, wo, out, out, out);
}

// Round 6
// 216.208 us; speedup vs baseline: 1.2017x; 1.1995x over previous
//
#include <hip/hip_runtime.h>
#include <hip/hip_bf16.h>

// MHA forward. f32 inputs (+int32 mask), f32 output; bf16 internal pipeline.
// B=2, S=2048, D_MODEL=1024, H=16, DK=64.
// [QKV proj GEMM z=3 (Q scaled 1/8; V transposed)] -> [flash attn, swapped-QK^T
//  in-register softmax] -> [O proj].

typedef short short8  __attribute__((ext_vector_type(8)));
typedef short short4v __attribute__((ext_vector_type(4)));
typedef float f32x4   __attribute__((ext_vector_type(4)));
typedef unsigned int uint4v __attribute__((ext_vector_type(4)));

#define D_MODEL 1024
#define SEQ     2048
#define NHEAD   16
#define DKD     64
#define HSTR    (SEQ * DKD)

#define MFMA16(a, b, c) __builtin_amdgcn_mfma_f32_16x16x32_bf16((a), (b), (c), 0, 0, 0)

__device__ __forceinline__ ushort f2bf(float f) {
    union { float f; unsigned u; } a; a.f = f;
    unsigned r = a.u + 0x7fffu + ((a.u >> 16) & 1u);
    return (ushort)(r >> 16);
}
// packed f32x2 -> bf16x2 (RNE), lo -> bits[15:0]
__device__ __forceinline__ unsigned cvtpk(float lo, float hi) {
    unsigned r;
    asm("v_cvt_pk_bf16_f32 %0, %1, %2" : "=v"(r) : "v"(lo), "v"(hi));
    return r;
}
union U16 { uint4v u; short8 s; };

// frag read from swizzled tile, row byte-stride 128 (64-col tiles)
__device__ __forceinline__ short8 frag128(const ushort* base, int row, int c0) {
    int cb = (c0 * 2) ^ ((row & 7) << 4);
    return *(const short8*)((const char*)base + row * 128 + cb);
}
// frag read from swizzled tile, row byte-stride 256 (128-col tiles)
__device__ __forceinline__ short8 frag256(const ushort* base, int row, int c0) {
    int cb = (c0 * 2) ^ ((row & 7) << 4);
    return *(const short8*)((const char*)base + row * 256 + cb);
}

// ---------------------------------------------------------------------------
// GEMM: C[4096][1024] = A[4096][1024] * W[1024][1024]^T (NT).
// LAYOUT 0 (QKV): z==0 -> head-split bf16 scaled 0.125 (Q); z==1 -> head-split (K);
//                 z==2 -> transposed bf16 [bh][dk][s] (V).
// LAYOUT 1: plain f32 out[m*1024+n] (O-proj).
// Staging converts f32->bf16 with v_cvt_pk_bf16_f32 (was the VALU bottleneck).
// ---------------------------------------------------------------------------
template<int LAYOUT, int A_BF16>
__global__ __launch_bounds__(256, 2) void gemm_nt(
    const void* __restrict__ A0, const void* __restrict__ A1, const void* __restrict__ A2,
    const float* __restrict__ W0, const float* __restrict__ W1, const float* __restrict__ W2,
    void* __restrict__ O0, void* __restrict__ O1, void* __restrict__ O2)
{
    const int z = blockIdx.z;
    const void*  A = (z == 0) ? A0 : ((z == 1) ? A1 : A2);
    const float* W = (z == 0) ? W0 : ((z == 1) ? W1 : W2);
    void* O        = (z == 0) ? O0 : ((z == 1) ? O1 : O2);

    const int bm = blockIdx.x * 128;
    const int bn = blockIdx.y * 128;
    const int tid = threadIdx.x;
    const int w = tid >> 6, l = tid & 63;
    const int wr = w >> 1, wc = w & 1;

    __shared__ ushort sm[16384];

    f32x4 acc[4][4] = {};

    for (int t = 0; t < 16; ++t) {
        __syncthreads();
        #pragma unroll
        for (int i = 0; i < 4; ++i) {
            int flat = i * 256 + tid;
            int row  = flat >> 3;
            int c8   = (flat & 7) << 3;
            int cb   = (c8 * 2) ^ ((row & 7) << 4);
            short8 av;
            if (A_BF16) {
                av = *(const short8*)((const ushort*)A + (size_t)(bm + row) * 1024 + t * 64 + c8);
            } else {
                const float* ap = (const float*)A + (size_t)(bm + row) * 1024 + t * 64 + c8;
                f32x4 x0 = *(const f32x4*)ap, x1 = *(const f32x4*)(ap + 4);
                U16 cv;
                cv.u[0] = cvtpk(x0[0], x0[1]); cv.u[1] = cvtpk(x0[2], x0[3]);
                cv.u[2] = cvtpk(x1[0], x1[1]); cv.u[3] = cvtpk(x1[2], x1[3]);
                av = cv.s;
            }
            *(short8*)((char*)sm + row * 128 + cb) = av;

            const float* wp = W + (size_t)(bn + row) * 1024 + t * 64 + c8;
            f32x4 y0 = *(const f32x4*)wp, y1 = *(const f32x4*)(wp + 4);
            U16 wv;
            wv.u[0] = cvtpk(y0[0], y0[1]); wv.u[1] = cvtpk(y0[2], y0[3]);
            wv.u[2] = cvtpk(y1[0], y1[1]); wv.u[3] = cvtpk(y1[2], y1[3]);
            *(short8*)((char*)(sm + 8192) + row * 128 + cb) = wv.s;
        }
        __syncthreads();

        #pragma unroll
        for (int kk = 0; kk < 2; ++kk) {
            const int c0 = kk * 32 + ((l >> 4) << 3);
            short8 af[4], bf[4];
            #pragma unroll
            for (int mi = 0; mi < 4; ++mi)
                af[mi] = frag128(sm, wr * 64 + mi * 16 + (l & 15), c0);
            #pragma unroll
            for (int ni = 0; ni < 4; ++ni)
                bf[ni] = frag128(sm + 8192, wc * 64 + ni * 16 + (l & 15), c0);
            #pragma unroll
            for (int mi = 0; mi < 4; ++mi)
                #pragma unroll
                for (int ni = 0; ni < 4; ++ni)
                    acc[mi][ni] = MFMA16(af[mi], bf[ni], acc[mi][ni]);
        }
    }

    const float sc = (LAYOUT == 0 && z == 0) ? 0.125f : 1.0f;
    #pragma unroll
    for (int mi = 0; mi < 4; ++mi) {
        #pragma unroll
        for (int ni = 0; ni < 4; ++ni) {
            #pragma unroll
            for (int j = 0; j < 4; ++j) {
                int m = bm + wr * 64 + mi * 16 + ((l >> 4) << 2) + j;
                int n = bn + wc * 64 + ni * 16 + (l & 15);
                if (LAYOUT == 0) {
                    int b = m >> 11, s = m & 2047, h = n >> 6, dk = n & 63;
                    if (z == 2)
                        ((ushort*)O)[(size_t)(b * NHEAD + h) * HSTR + dk * SEQ + s] = f2bf(acc[mi][ni][j]);
                    else
                        ((ushort*)O)[(size_t)(b * NHEAD + h) * HSTR + s * DKD + dk] = f2bf(acc[mi][ni][j] * sc);
                } else {
                    ((float*)O)[(size_t)m * 1024 + n] = acc[mi][ni][j];
                }
            }
        }
    }
}

// ---------------------------------------------------------------------------
// Flash attention, swapped QK^T: S^T = mfma(K, Q) puts a full q-row of P in each
// lane -> in-register softmax (tree + 2 shfls), zero-shuffle P->A-frag packing
// (kphys=kk*32+hi*8+u <-> klog=ni*16+hi*4+j; V staged k-permuted to match).
// QBLK=64 (4 waves x 16 q-rows), KVBLK=128, 16 tiles, 2 barriers/tile.
// ---------------------------------------------------------------------------
__global__ __launch_bounds__(256, 4) void attn_fwd(
    const ushort* __restrict__ Q, const ushort* __restrict__ K, const ushort* __restrict__ Vt,
    const int* __restrict__ mask, ushort* __restrict__ ctx)
{
    const int tid = threadIdx.x;
    const int w = tid >> 6, l = tid & 63;
    const int hi = l >> 4, lo = l & 15;
    const int id  = blockIdx.x;
    const int nid = (id & 7) * 128 + (id >> 3);    // XCD-chunked: 4 bh per XCD
    const int bh  = nid >> 5;
    const int q0  = (nid & 31) * 64;
    const int b   = bh >> 4, h = bh & 15;

    __shared__ ushort sm[16384];   // [0,8192): K [128][64] swz; [8192,16384): V [64][128] swz, kphys order

    const ushort* Qh = Q  + (size_t)bh * HSTR;
    const ushort* Kh = K  + (size_t)bh * HSTR;
    const ushort* Vh = Vt + (size_t)bh * HSTR;     // [dk][s]

    // Q fragments (B operand): q-row = lo, dk = kk*32 + hi*8 .. +7
    short8 qf[2];
    #pragma unroll
    for (int kk = 0; kk < 2; ++kk)
        qf[kk] = *(const short8*)(Qh + (size_t)(q0 + w * 16 + lo) * DKD + kk * 32 + hi * 8);

    f32x4 acc_o[4] = {};
    float m_run = -INFINITY, l_run = 0.0f;         // per-lane state for q-row = lo

    // staging decomposition
    const int kr = tid >> 3;              // K row base (0..31), +i*32
    const int kc = (tid & 7) << 3;        // K col (elems)
    const int vr = tid >> 4;              // V dk-row base (0..15), +i*16
    const int vkk = (tid >> 2) & 3;       // V kp: kk
    const int vhi = tid & 3;              // V kp: hi
    const int vkpb = (tid & 15) << 4;     // V kp-run byte offset (16B)

    short8  kreg[4];
    short4v vreg0[4], vreg1[4];

    #define LOADT(kt_) {                                                                   \
        _Pragma("unroll")                                                                  \
        for (int i = 0; i < 4; ++i)                                                        \
            kreg[i] = *(const short8*)(Kh + (size_t)((kt_) * 128 + i * 32 + kr) * DKD + kc); \
        _Pragma("unroll")                                                                  \
        for (int i = 0; i < 4; ++i) {                                                      \
            const ushort* vp = Vh + (size_t)(i * 16 + vr) * SEQ + (kt_) * 128 + vkk * 32 + vhi * 4; \
            vreg0[i] = *(const short4v*)(vp);                                              \
            vreg1[i] = *(const short4v*)(vp + 16); } }

    #define WRITET() {                                                                     \
        _Pragma("unroll")                                                                  \
        for (int i = 0; i < 4; ++i) {                                                      \
            int r = i * 32 + kr;                                                           \
            *(short8*)((char*)sm + r * 128 + ((kc * 2) ^ ((r & 7) << 4))) = kreg[i]; }     \
        _Pragma("unroll")                                                                  \
        for (int i = 0; i < 4; ++i) {                                                      \
            int r = i * 16 + vr;                                                           \
            char* p = (char*)(sm + 8192) + r * 256 + (vkpb ^ ((r & 7) << 4));              \
            *(short4v*)(p)     = vreg0[i];                                                 \
            *(short4v*)(p + 8) = vreg1[i]; } }

    LOADT(0); WRITET();
    __syncthreads();

    #pragma unroll 1
    for (int kt = 0; kt < 16; ++kt) {
        // --- QK^T: s4[ni] C-layout: kv-row = ni*16 + hi*4 + j, q-col = lo
        f32x4 s4[8] = {};
        __builtin_amdgcn_s_setprio(1);
        #pragma unroll
        for (int kk = 0; kk < 2; ++kk) {
            const int c0 = kk * 32 + hi * 8;
            #pragma unroll
            for (int ni = 0; ni < 8; ++ni) {
                short8 kf = frag128(sm, ni * 16 + lo, c0);
                s4[ni] = MFMA16(kf, qf[kk], s4[ni]);
            }
        }
        __builtin_amdgcn_s_setprio(0);

        if (kt < 15) LOADT(kt + 1);        // issue next tile; latency hides under softmax+PV

        // --- mask (exact masked_fill semantics, pre-max)
        const int* mrow = mask + b * SEQ + kt * 128 + hi * 4;
        #pragma unroll
        for (int ni = 0; ni < 8; ++ni) {
            int4 mv = *(const int4*)(mrow + ni * 16);
            s4[ni][0] = mv.x ? s4[ni][0] : -1e9f;
            s4[ni][1] = mv.y ? s4[ni][1] : -1e9f;
            s4[ni][2] = mv.z ? s4[ni][2] : -1e9f;
            s4[ni][3] = mv.w ? s4[ni][3] : -1e9f;
        }

        // --- row max: in-register tree + 2 shfls (4 lanes per q-row)
        float tmx[8];
        #pragma unroll
        for (int ni = 0; ni < 8; ++ni)
            tmx[ni] = fmaxf(fmaxf(s4[ni][0], s4[ni][1]), fmaxf(s4[ni][2], s4[ni][3]));
        float t = fmaxf(fmaxf(fmaxf(tmx[0], tmx[1]), fmaxf(tmx[2], tmx[3])),
                        fmaxf(fmaxf(tmx[4], tmx[5]), fmaxf(tmx[6], tmx[7])));
        t = fmaxf(t, __shfl_xor(t, 16));
        t = fmaxf(t, __shfl_xor(t, 32));

        if (__any(t > m_run)) {            // rescale (exact; skipped when no row grows)
            float mnew = fmaxf(m_run, t);
            float c = __expf(m_run - mnew);
            m_run = mnew;
            l_run *= c;
            float cj[4];
            #pragma unroll
            for (int j = 0; j < 4; ++j)
                cj[j] = __shfl(c, (l & 48) | (hi * 4 + j));
            #pragma unroll
            for (int ni = 0; ni < 4; ++ni)
                #pragma unroll
                for (int j = 0; j < 4; ++j) acc_o[ni][j] *= cj[j];
        }

        // --- exp + row sum
        float rs[8];
        #pragma unroll
        for (int ni = 0; ni < 8; ++ni) {
            #pragma unroll
            for (int j = 0; j < 4; ++j) s4[ni][j] = __expf(s4[ni][j] - m_run);
            rs[ni] = (s4[ni][0] + s4[ni][1]) + (s4[ni][2] + s4[ni][3]);
        }
        float rsum = ((rs[0] + rs[1]) + (rs[2] + rs[3])) + ((rs[4] + rs[5]) + (rs[6] + rs[7]));
        rsum += __shfl_xor(rsum, 16);
        rsum += __shfl_xor(rsum, 32);
        l_run += rsum;

        // --- pack P into A-frags (zero cross-lane; kphys mapping)
        short8 pa[4];
        #pragma unroll
        for (int kk = 0; kk < 4; ++kk) {
            U16 cv;
            cv.u[0] = cvtpk(s4[2 * kk][0],     s4[2 * kk][1]);
            cv.u[1] = cvtpk(s4[2 * kk][2],     s4[2 * kk][3]);
            cv.u[2] = cvtpk(s4[2 * kk + 1][0], s4[2 * kk + 1][1]);
            cv.u[3] = cvtpk(s4[2 * kk + 1][2], s4[2 * kk + 1][3]);
            pa[kk] = cv.s;
        }

        // --- PV: acc C-layout: q-row = hi*4+j, dk-col = ni*16 + lo
        __builtin_amdgcn_s_setprio(1);
        #pragma unroll
        for (int kk = 0; kk < 4; ++kk) {
            const int c0 = kk * 32 + hi * 8;
            #pragma unroll
            for (int ni = 0; ni < 4; ++ni) {
                short8 vf = frag256(sm + 8192, ni * 16 + lo, c0);
                acc_o[ni] = MFMA16(pa[kk], vf, acc_o[ni]);
            }
        }
        __builtin_amdgcn_s_setprio(0);

        __syncthreads();                   // reads of tile kt done
        if (kt < 15) {
            WRITET();
            __syncthreads();               // tile kt+1 staged
        }
    }

    // --- epilogue: normalize, write context [b][s][h*64+dk]
    float inv = 1.0f / l_run;              // for q-row = lo
    float invj[4];
    #pragma unroll
    for (int j = 0; j < 4; ++j)
        invj[j] = __shfl(inv, (l & 48) | (hi * 4 + j));
    #pragma unroll
    for (int ni = 0; ni < 4; ++ni)
        #pragma unroll
        for (int j = 0; j < 4; ++j) {
            int qg = q0 + w * 16 + hi * 4 + j;
            ctx[(size_t)(b * SEQ + qg) * D_MODEL + h * DKD + ni * 16 + lo] = f2bf(acc_o[ni][j] * invj[j]);
        }
    #undef LOADT
    #undef WRITET
}

__global__ void ws_sentinel(float* __restrict__ out, int n, float code) {
    int i = blockIdx.x * blockDim.x + threadIdx.x;
    if (i < n) out[i] = (i == 0) ? code : 0.0f;
}

// ---------------------------------------------------------------------------
extern "C" void kernel_launch(void* const* d_in, const int* in_sizes, int n_in,
                              void* d_out, int out_size, void* d_ws, size_t ws_size,
                              hipStream_t stream) {
    const float* q    = (const float*)d_in[0];
    const float* k    = (const float*)d_in[1];
    const float* v    = (const float*)d_in[2];
    const int*   mask = (const int*)d_in[3];
    const float* wq   = (const float*)d_in[4];
    const float* wk   = (const float*)d_in[5];
    const float* wv   = (const float*)d_in[6];
    const float* wo   = (const float*)d_in[7];
    float* out = (float*)d_out;

    if (ws_size < (size_t)33554432) {
        float code = 100.0f + (float)(ws_size >> 20);
        ws_sentinel<<<(out_size + 255) / 256, 256, 0, stream>>>(out, out_size, code);
        return;
    }

    ushort* ws = (ushort*)d_ws;
    ushort* Qb = ws;                       // [bh][s][dk] bf16 (scaled 1/8)
    ushort* Kb = ws + 4194304;             // [bh][s][dk]
    ushort* Vb = ws + 8388608;             // [bh][dk][s]  (transposed)
    ushort* Cb = ws + 12582912;            // context [b,s,d] bf16

    dim3 blk(256, 1, 1);
    gemm_nt<0, 0><<<dim3(32, 8, 3), blk, 0, stream>>>(q, k, v, wq, wk, wv, Qb, Kb, Vb);
    attn_fwd<<<dim3(1024, 1, 1), blk, 0, stream>>>(Qb, Kb, Vb, mask, Cb);
    gemm_nt<1, 1><<<dim3(32, 8, 1), blk, 0, stream>>>(Cb, Cb, Cb, wo, wo, wo, out, out, out);
}

// Round 7
// 186.301 us; speedup vs baseline: 1.3946x; 1.1605x over previous
//
#include <hip/hip_runtime.h>
#include <hip/hip_bf16.h>

// MHA forward. f32 inputs (+int32 mask), f32 output; bf16 internal pipeline.
// B=2, S=2048, D_MODEL=1024, H=16, DK=64.
// [QKV proj GEMM z=3 (Q scaled 1/8; V transposed), T14 prefetch] ->
// [flash attn, swapped-QK^T in-register softmax] -> [O proj, T14 prefetch].

typedef short short8  __attribute__((ext_vector_type(8)));
typedef short short4v __attribute__((ext_vector_type(4)));
typedef float f32x4   __attribute__((ext_vector_type(4)));
typedef unsigned int uint4v __attribute__((ext_vector_type(4)));

#define D_MODEL 1024
#define SEQ     2048
#define NHEAD   16
#define DKD     64
#define HSTR    (SEQ * DKD)

#define MFMA16(a, b, c) __builtin_amdgcn_mfma_f32_16x16x32_bf16((a), (b), (c), 0, 0, 0)

__device__ __forceinline__ ushort f2bf(float f) {
    union { float f; unsigned u; } a; a.f = f;
    unsigned r = a.u + 0x7fffu + ((a.u >> 16) & 1u);
    return (ushort)(r >> 16);
}
// packed f32x2 -> bf16x2 (RNE), lo -> bits[15:0]  (used only in attn P-pack)
__device__ __forceinline__ unsigned cvtpk(float lo, float hi) {
    unsigned r;
    asm("v_cvt_pk_bf16_f32 %0, %1, %2" : "=v"(r) : "v"(lo), "v"(hi));
    return r;
}
union U16 { uint4v u; short8 s; };

// frag read from swizzled tile, row byte-stride 128 (64-col tiles)
__device__ __forceinline__ short8 frag128(const ushort* base, int row, int c0) {
    int cb = (c0 * 2) ^ ((row & 7) << 4);
    return *(const short8*)((const char*)base + row * 128 + cb);
}
// frag read from swizzled tile, row byte-stride 256 (128-col tiles)
__device__ __forceinline__ short8 frag256(const ushort* base, int row, int c0) {
    int cb = (c0 * 2) ^ ((row & 7) << 4);
    return *(const short8*)((const char*)base + row * 256 + cb);
}

// ---------------------------------------------------------------------------
// GEMM: C[4096][1024] = A[4096][1024] * W[1024][1024]^T (NT).
// LAYOUT 0 (QKV): z==0 -> head-split bf16 scaled 0.125 (Q); z==1 -> head-split (K);
//                 z==2 -> transposed bf16 [bh][dk][s] (V).
// LAYOUT 1: plain f32 out[m*1024+n] (O-proj).
// T14 async-stage: tile t+1 global->reg loads issued under tile t's MFMAs;
// reg->LDS write lands after the read-done barrier. Scalar f2bf (m240: no asm cvtpk).
// ---------------------------------------------------------------------------
template<int LAYOUT, int A_BF16>
__global__ __launch_bounds__(256, 3) void gemm_nt(
    const void* __restrict__ A0, const void* __restrict__ A1, const void* __restrict__ A2,
    const float* __restrict__ W0, const float* __restrict__ W1, const float* __restrict__ W2,
    void* __restrict__ O0, void* __restrict__ O1, void* __restrict__ O2)
{
    const int z = blockIdx.z;
    const void*  A = (z == 0) ? A0 : ((z == 1) ? A1 : A2);
    const float* W = (z == 0) ? W0 : ((z == 1) ? W1 : W2);
    void* O        = (z == 0) ? O0 : ((z == 1) ? O1 : O2);

    const int bm = blockIdx.x * 128;
    const int bn = blockIdx.y * 128;
    const int tid = threadIdx.x;
    const int w = tid >> 6, l = tid & 63;
    const int wr = w >> 1, wc = w & 1;

    __shared__ ushort sm[16384];   // A tile [0,8192) [128][64] swz; W tile [8192,16384)

    f32x4 acc[4][4] = {};
    short8 areg[4], wreg[4];
    const int srow = tid >> 3;              // 0..31, +i*32
    const int sc8  = (tid & 7) << 3;        // col base (elems)
    const int scb  = (sc8 * 2);             // col byte (pre-XOR)

    #define GLOADT(t_) {                                                                    \
        _Pragma("unroll")                                                                   \
        for (int i = 0; i < 4; ++i) {                                                       \
            int row = i * 32 + srow;                                                        \
            if (A_BF16) {                                                                   \
                areg[i] = *(const short8*)((const ushort*)A + (size_t)(bm + row) * 1024 + (t_) * 64 + sc8); \
            } else {                                                                        \
                const float* ap = (const float*)A + (size_t)(bm + row) * 1024 + (t_) * 64 + sc8; \
                f32x4 x0 = *(const f32x4*)ap, x1 = *(const f32x4*)(ap + 4);                 \
                _Pragma("unroll")                                                           \
                for (int u = 0; u < 4; ++u) { areg[i][u] = (short)f2bf(x0[u]); areg[i][4 + u] = (short)f2bf(x1[u]); } \
            }                                                                               \
            const float* wp = W + (size_t)(bn + row) * 1024 + (t_) * 64 + sc8;              \
            f32x4 y0 = *(const f32x4*)wp, y1 = *(const f32x4*)(wp + 4);                     \
            _Pragma("unroll")                                                               \
            for (int u = 0; u < 4; ++u) { wreg[i][u] = (short)f2bf(y0[u]); wreg[i][4 + u] = (short)f2bf(y1[u]); } \
        } }

    #define GWRITET() {                                                                     \
        _Pragma("unroll")                                                                   \
        for (int i = 0; i < 4; ++i) {                                                       \
            int row = i * 32 + srow;                                                        \
            int cb  = scb ^ ((row & 7) << 4);                                               \
            *(short8*)((char*)sm + row * 128 + cb) = areg[i];                               \
            *(short8*)((char*)(sm + 8192) + row * 128 + cb) = wreg[i];                      \
        } }

    GLOADT(0);
    #pragma unroll 1
    for (int t = 0; t < 16; ++t) {
        GWRITET();
        __syncthreads();                    // tile t staged
        if (t < 15) GLOADT(t + 1);          // in flight under MFMAs

        #pragma unroll
        for (int kk = 0; kk < 2; ++kk) {
            const int c0 = kk * 32 + ((l >> 4) << 3);
            short8 af[4], bf[4];
            #pragma unroll
            for (int mi = 0; mi < 4; ++mi)
                af[mi] = frag128(sm, wr * 64 + mi * 16 + (l & 15), c0);
            #pragma unroll
            for (int ni = 0; ni < 4; ++ni)
                bf[ni] = frag128(sm + 8192, wc * 64 + ni * 16 + (l & 15), c0);
            #pragma unroll
            for (int mi = 0; mi < 4; ++mi)
                #pragma unroll
                for (int ni = 0; ni < 4; ++ni)
                    acc[mi][ni] = MFMA16(af[mi], bf[ni], acc[mi][ni]);
        }
        __syncthreads();                    // tile t reads done
    }
    #undef GLOADT
    #undef GWRITET

    const float sc = (LAYOUT == 0 && z == 0) ? 0.125f : 1.0f;
    #pragma unroll
    for (int mi = 0; mi < 4; ++mi) {
        #pragma unroll
        for (int ni = 0; ni < 4; ++ni) {
            #pragma unroll
            for (int j = 0; j < 4; ++j) {
                int m = bm + wr * 64 + mi * 16 + ((l >> 4) << 2) + j;
                int n = bn + wc * 64 + ni * 16 + (l & 15);
                if (LAYOUT == 0) {
                    int b = m >> 11, s = m & 2047, h = n >> 6, dk = n & 63;
                    if (z == 2)
                        ((ushort*)O)[(size_t)(b * NHEAD + h) * HSTR + dk * SEQ + s] = f2bf(acc[mi][ni][j]);
                    else
                        ((ushort*)O)[(size_t)(b * NHEAD + h) * HSTR + s * DKD + dk] = f2bf(acc[mi][ni][j] * sc);
                } else {
                    ((float*)O)[(size_t)m * 1024 + n] = acc[mi][ni][j];
                }
            }
        }
    }
}

// ---------------------------------------------------------------------------
// Flash attention, swapped QK^T: S^T = mfma(K, Q) puts a full q-row of P in each
// lane -> in-register softmax (tree + 2 shfls), zero-shuffle P->A-frag packing
// (kphys=kk*32+hi*8+u <-> klog=ni*16+hi*4+j; V staged k-permuted to match).
// QBLK=64 (4 waves x 16 q-rows), KVBLK=128, 16 tiles, 2 barriers/tile.
// ---------------------------------------------------------------------------
__global__ __launch_bounds__(256, 4) void attn_fwd(
    const ushort* __restrict__ Q, const ushort* __restrict__ K, const ushort* __restrict__ Vt,
    const int* __restrict__ mask, ushort* __restrict__ ctx)
{
    const int tid = threadIdx.x;
    const int w = tid >> 6, l = tid & 63;
    const int hi = l >> 4, lo = l & 15;
    const int id  = blockIdx.x;
    const int nid = (id & 7) * 128 + (id >> 3);    // XCD-chunked: 4 bh per XCD
    const int bh  = nid >> 5;
    const int q0  = (nid & 31) * 64;
    const int b   = bh >> 4, h = bh & 15;

    __shared__ ushort sm[16384];   // [0,8192): K [128][64] swz; [8192,16384): V [64][128] swz, kphys order

    const ushort* Qh = Q  + (size_t)bh * HSTR;
    const ushort* Kh = K  + (size_t)bh * HSTR;
    const ushort* Vh = Vt + (size_t)bh * HSTR;     // [dk][s]

    // Q fragments (B operand): q-row = lo, dk = kk*32 + hi*8 .. +7
    short8 qf[2];
    #pragma unroll
    for (int kk = 0; kk < 2; ++kk)
        qf[kk] = *(const short8*)(Qh + (size_t)(q0 + w * 16 + lo) * DKD + kk * 32 + hi * 8);

    f32x4 acc_o[4] = {};
    float m_run = -INFINITY, l_run = 0.0f;         // per-lane state for q-row = lo

    const int kr = tid >> 3;              // K row base (0..31), +i*32
    const int kc = (tid & 7) << 3;        // K col (elems)
    const int vr = tid >> 4;              // V dk-row base (0..15), +i*16
    const int vkk = (tid >> 2) & 3;       // V kp: kk
    const int vhi = tid & 3;              // V kp: hi
    const int vkpb = (tid & 15) << 4;     // V kp-run byte offset (16B)

    short8  kreg[4];
    short4v vreg0[4], vreg1[4];

    #define LOADT(kt_) {                                                                   \
        _Pragma("unroll")                                                                  \
        for (int i = 0; i < 4; ++i)                                                        \
            kreg[i] = *(const short8*)(Kh + (size_t)((kt_) * 128 + i * 32 + kr) * DKD + kc); \
        _Pragma("unroll")                                                                  \
        for (int i = 0; i < 4; ++i) {                                                      \
            const ushort* vp = Vh + (size_t)(i * 16 + vr) * SEQ + (kt_) * 128 + vkk * 32 + vhi * 4; \
            vreg0[i] = *(const short4v*)(vp);                                              \
            vreg1[i] = *(const short4v*)(vp + 16); } }

    #define WRITET() {                                                                     \
        _Pragma("unroll")                                                                  \
        for (int i = 0; i < 4; ++i) {                                                      \
            int r = i * 32 + kr;                                                           \
            *(short8*)((char*)sm + r * 128 + ((kc * 2) ^ ((r & 7) << 4))) = kreg[i]; }     \
        _Pragma("unroll")                                                                  \
        for (int i = 0; i < 4; ++i) {                                                      \
            int r = i * 16 + vr;                                                           \
            char* p = (char*)(sm + 8192) + r * 256 + (vkpb ^ ((r & 7) << 4));              \
            *(short4v*)(p)     = vreg0[i];                                                 \
            *(short4v*)(p + 8) = vreg1[i]; } }

    LOADT(0); WRITET();
    __syncthreads();

    #pragma unroll 1
    for (int kt = 0; kt < 16; ++kt) {
        // --- QK^T: s4[ni] C-layout: kv-row = ni*16 + hi*4 + j, q-col = lo
        f32x4 s4[8] = {};
        __builtin_amdgcn_s_setprio(1);
        #pragma unroll
        for (int kk = 0; kk < 2; ++kk) {
            const int c0 = kk * 32 + hi * 8;
            #pragma unroll
            for (int ni = 0; ni < 8; ++ni) {
                short8 kf = frag128(sm, ni * 16 + lo, c0);
                s4[ni] = MFMA16(kf, qf[kk], s4[ni]);
            }
        }
        __builtin_amdgcn_s_setprio(0);

        if (kt < 15) LOADT(kt + 1);        // issue next tile; latency hides under softmax+PV

        // --- mask (exact masked_fill semantics, pre-max)
        const int* mrow = mask + b * SEQ + kt * 128 + hi * 4;
        #pragma unroll
        for (int ni = 0; ni < 8; ++ni) {
            int4 mv = *(const int4*)(mrow + ni * 16);
            s4[ni][0] = mv.x ? s4[ni][0] : -1e9f;
            s4[ni][1] = mv.y ? s4[ni][1] : -1e9f;
            s4[ni][2] = mv.z ? s4[ni][2] : -1e9f;
            s4[ni][3] = mv.w ? s4[ni][3] : -1e9f;
        }

        // --- row max: in-register tree + 2 shfls (4 lanes per q-row)
        float tmx[8];
        #pragma unroll
        for (int ni = 0; ni < 8; ++ni)
            tmx[ni] = fmaxf(fmaxf(s4[ni][0], s4[ni][1]), fmaxf(s4[ni][2], s4[ni][3]));
        float t = fmaxf(fmaxf(fmaxf(tmx[0], tmx[1]), fmaxf(tmx[2], tmx[3])),
                        fmaxf(fmaxf(tmx[4], tmx[5]), fmaxf(tmx[6], tmx[7])));
        t = fmaxf(t, __shfl_xor(t, 16));
        t = fmaxf(t, __shfl_xor(t, 32));

        if (__any(t > m_run)) {            // rescale (exact; skipped when no row grows)
            float mnew = fmaxf(m_run, t);
            float c = __expf(m_run - mnew);
            m_run = mnew;
            l_run *= c;
            float cj[4];
            #pragma unroll
            for (int j = 0; j < 4; ++j)
                cj[j] = __shfl(c, (l & 48) | (hi * 4 + j));
            #pragma unroll
            for (int ni = 0; ni < 4; ++ni)
                #pragma unroll
                for (int j = 0; j < 4; ++j) acc_o[ni][j] *= cj[j];
        }

        // --- exp + row sum
        float rs[8];
        #pragma unroll
        for (int ni = 0; ni < 8; ++ni) {
            #pragma unroll
            for (int j = 0; j < 4; ++j) s4[ni][j] = __expf(s4[ni][j] - m_run);
            rs[ni] = (s4[ni][0] + s4[ni][1]) + (s4[ni][2] + s4[ni][3]);
        }
        float rsum = ((rs[0] + rs[1]) + (rs[2] + rs[3])) + ((rs[4] + rs[5]) + (rs[6] + rs[7]));
        rsum += __shfl_xor(rsum, 16);
        rsum += __shfl_xor(rsum, 32);
        l_run += rsum;

        // --- pack P into A-frags (zero cross-lane; kphys mapping)
        short8 pa[4];
        #pragma unroll
        for (int kk = 0; kk < 4; ++kk) {
            U16 cv;
            cv.u[0] = cvtpk(s4[2 * kk][0],     s4[2 * kk][1]);
            cv.u[1] = cvtpk(s4[2 * kk][2],     s4[2 * kk][3]);
            cv.u[2] = cvtpk(s4[2 * kk + 1][0], s4[2 * kk + 1][1]);
            cv.u[3] = cvtpk(s4[2 * kk + 1][2], s4[2 * kk + 1][3]);
            pa[kk] = cv.s;
        }

        // --- PV: acc C-layout: q-row = hi*4+j, dk-col = ni*16 + lo
        __builtin_amdgcn_s_setprio(1);
        #pragma unroll
        for (int kk = 0; kk < 4; ++kk) {
            const int c0 = kk * 32 + hi * 8;
            #pragma unroll
            for (int ni = 0; ni < 4; ++ni) {
                short8 vf = frag256(sm + 8192, ni * 16 + lo, c0);
                acc_o[ni] = MFMA16(pa[kk], vf, acc_o[ni]);
            }
        }
        __builtin_amdgcn_s_setprio(0);

        __syncthreads();                   // reads of tile kt done
        if (kt < 15) {
            WRITET();
            __syncthreads();               // tile kt+1 staged
        }
    }

    // --- epilogue: normalize, write context [b][s][h*64+dk]
    float inv = 1.0f / l_run;              // for q-row = lo
    float invj[4];
    #pragma unroll
    for (int j = 0; j < 4; ++j)
        invj[j] = __shfl(inv, (l & 48) | (hi * 4 + j));
    #pragma unroll
    for (int ni = 0; ni < 4; ++ni)
        #pragma unroll
        for (int j = 0; j < 4; ++j) {
            int qg = q0 + w * 16 + hi * 4 + j;
            ctx[(size_t)(b * SEQ + qg) * D_MODEL + h * DKD + ni * 16 + lo] = f2bf(acc_o[ni][j] * invj[j]);
        }
    #undef LOADT
    #undef WRITET
}

__global__ void ws_sentinel(float* __restrict__ out, int n, float code) {
    int i = blockIdx.x * blockDim.x + threadIdx.x;
    if (i < n) out[i] = (i == 0) ? code : 0.0f;
}

// ---------------------------------------------------------------------------
extern "C" void kernel_launch(void* const* d_in, const int* in_sizes, int n_in,
                              void* d_out, int out_size, void* d_ws, size_t ws_size,
                              hipStream_t stream) {
    const float* q    = (const float*)d_in[0];
    const float* k    = (const float*)d_in[1];
    const float* v    = (const float*)d_in[2];
    const int*   mask = (const int*)d_in[3];
    const float* wq   = (const float*)d_in[4];
    const float* wk   = (const float*)d_in[5];
    const float* wv   = (const float*)d_in[6];
    const float* wo   = (const float*)d_in[7];
    float* out = (float*)d_out;

    if (ws_size < (size_t)33554432) {
        float code = 100.0f + (float)(ws_size >> 20);
        ws_sentinel<<<(out_size + 255) / 256, 256, 0, stream>>>(out, out_size, code);
        return;
    }

    ushort* ws = (ushort*)d_ws;
    ushort* Qb = ws;                       // [bh][s][dk] bf16 (scaled 1/8)
    ushort* Kb = ws + 4194304;             // [bh][s][dk]
    ushort* Vb = ws + 8388608;             // [bh][dk][s]  (transposed)
    ushort* Cb = ws + 12582912;            // context [b,s,d] bf16

    dim3 blk(256, 1, 1);
    gemm_nt<0, 0><<<dim3(32, 8, 3), blk, 0, stream>>>(q, k, v, wq, wk, wv, Qb, Kb, Vb);
    attn_fwd<<<dim3(1024, 1, 1), blk, 0, stream>>>(Qb, Kb, Vb, mask, Cb);
    gemm_nt<1, 1><<<dim3(32, 8, 1), blk, 0, stream>>>(Cb, Cb, Cb, wo, wo, wo, out, out, out);
}

// Round 9
// 181.693 us; speedup vs baseline: 1.4300x; 1.0254x over previous
//
#include <hip/hip_runtime.h>
#include <hip/hip_bf16.h>

// MHA forward. f32 inputs (+int32 mask), f32 output; bf16 internal pipeline.
// B=2, S=2048, D_MODEL=1024, H=16, DK=64.
// [QKV proj GEMM z=3 (Q scaled 0.125*log2e; V transposed), T14 prefetch] ->
// [flash attn, swapped-QK^T in-register softmax, half-tile pipelined, exp2 domain]
// -> [O proj, T14 prefetch].

typedef short short8  __attribute__((ext_vector_type(8)));
typedef short short4v __attribute__((ext_vector_type(4)));
typedef float f32x4   __attribute__((ext_vector_type(4)));
typedef unsigned int uint4v __attribute__((ext_vector_type(4)));

#define D_MODEL 1024
#define SEQ     2048
#define NHEAD   16
#define DKD     64
#define HSTR    (SEQ * DKD)
#define QSCALE  0.1803368801111204f   // 0.125 * log2(e): exp2-domain softmax
#define EXP2F(x) exp2f(x)             // device exp2f -> v_exp_f32 (HW is base-2)

#define MFMA16(a, b, c) __builtin_amdgcn_mfma_f32_16x16x32_bf16((a), (b), (c), 0, 0, 0)

__device__ __forceinline__ ushort f2bf(float f) {
    union { float f; unsigned u; } a; a.f = f;
    unsigned r = a.u + 0x7fffu + ((a.u >> 16) & 1u);
    return (ushort)(r >> 16);
}
// packed f32x2 -> bf16x2 (RNE), lo -> bits[15:0]  (attn P-pack only)
__device__ __forceinline__ unsigned cvtpk(float lo, float hi) {
    unsigned r;
    asm("v_cvt_pk_bf16_f32 %0, %1, %2" : "=v"(r) : "v"(lo), "v"(hi));
    return r;
}
union U16 { uint4v u; short8 s; };

__device__ __forceinline__ short8 frag128(const ushort* base, int row, int c0) {
    int cb = (c0 * 2) ^ ((row & 7) << 4);
    return *(const short8*)((const char*)base + row * 128 + cb);
}
__device__ __forceinline__ short8 frag256(const ushort* base, int row, int c0) {
    int cb = (c0 * 2) ^ ((row & 7) << 4);
    return *(const short8*)((const char*)base + row * 256 + cb);
}

// ---------------------------------------------------------------------------
// GEMM: C[4096][1024] = A[4096][1024] * W[1024][1024]^T (NT).
// LAYOUT 0 (QKV): z==0 -> head-split bf16 scaled QSCALE (Q); z==1 -> head-split (K);
//                 z==2 -> transposed bf16 [bh][dk][s] (V).
// LAYOUT 1: plain f32 out[m*1024+n] (O-proj).
// T14 async-stage: tile t+1 global->reg loads under tile t's MFMAs.
// ---------------------------------------------------------------------------
template<int LAYOUT, int A_BF16>
__global__ __launch_bounds__(256, 3) void gemm_nt(
    const void* __restrict__ A0, const void* __restrict__ A1, const void* __restrict__ A2,
    const float* __restrict__ W0, const float* __restrict__ W1, const float* __restrict__ W2,
    void* __restrict__ O0, void* __restrict__ O1, void* __restrict__ O2)
{
    const int z = blockIdx.z;
    const void*  A = (z == 0) ? A0 : ((z == 1) ? A1 : A2);
    const float* W = (z == 0) ? W0 : ((z == 1) ? W1 : W2);
    void* O        = (z == 0) ? O0 : ((z == 1) ? O1 : O2);

    const int bm = blockIdx.x * 128;
    const int bn = blockIdx.y * 128;
    const int tid = threadIdx.x;
    const int w = tid >> 6, l = tid & 63;
    const int wr = w >> 1, wc = w & 1;

    __shared__ ushort sm[16384];

    f32x4 acc[4][4] = {};
    short8 areg[4], wreg[4];
    const int srow = tid >> 3;
    const int sc8  = (tid & 7) << 3;
    const int scb  = (sc8 * 2);

    #define GLOADT(t_) {                                                                    \
        _Pragma("unroll")                                                                   \
        for (int i = 0; i < 4; ++i) {                                                       \
            int row = i * 32 + srow;                                                        \
            if (A_BF16) {                                                                   \
                areg[i] = *(const short8*)((const ushort*)A + (size_t)(bm + row) * 1024 + (t_) * 64 + sc8); \
            } else {                                                                        \
                const float* ap = (const float*)A + (size_t)(bm + row) * 1024 + (t_) * 64 + sc8; \
                f32x4 x0 = *(const f32x4*)ap, x1 = *(const f32x4*)(ap + 4);                 \
                _Pragma("unroll")                                                           \
                for (int u = 0; u < 4; ++u) { areg[i][u] = (short)f2bf(x0[u]); areg[i][4 + u] = (short)f2bf(x1[u]); } \
            }                                                                               \
            const float* wp = W + (size_t)(bn + row) * 1024 + (t_) * 64 + sc8;              \
            f32x4 y0 = *(const f32x4*)wp, y1 = *(const f32x4*)(wp + 4);                     \
            _Pragma("unroll")                                                               \
            for (int u = 0; u < 4; ++u) { wreg[i][u] = (short)f2bf(y0[u]); wreg[i][4 + u] = (short)f2bf(y1[u]); } \
        } }

    #define GWRITET() {                                                                     \
        _Pragma("unroll")                                                                   \
        for (int i = 0; i < 4; ++i) {                                                       \
            int row = i * 32 + srow;                                                        \
            int cb  = scb ^ ((row & 7) << 4);                                               \
            *(short8*)((char*)sm + row * 128 + cb) = areg[i];                               \
            *(short8*)((char*)(sm + 8192) + row * 128 + cb) = wreg[i];                      \
        } }

    GLOADT(0);
    #pragma unroll 1
    for (int t = 0; t < 16; ++t) {
        GWRITET();
        __syncthreads();
        if (t < 15) GLOADT(t + 1);

        #pragma unroll
        for (int kk = 0; kk < 2; ++kk) {
            const int c0 = kk * 32 + ((l >> 4) << 3);
            short8 af[4], bf[4];
            #pragma unroll
            for (int mi = 0; mi < 4; ++mi)
                af[mi] = frag128(sm, wr * 64 + mi * 16 + (l & 15), c0);
            #pragma unroll
            for (int ni = 0; ni < 4; ++ni)
                bf[ni] = frag128(sm + 8192, wc * 64 + ni * 16 + (l & 15), c0);
            #pragma unroll
            for (int mi = 0; mi < 4; ++mi)
                #pragma unroll
                for (int ni = 0; ni < 4; ++ni)
                    acc[mi][ni] = MFMA16(af[mi], bf[ni], acc[mi][ni]);
        }
        __syncthreads();
    }
    #undef GLOADT
    #undef GWRITET

    const float sc = (LAYOUT == 0 && z == 0) ? QSCALE : 1.0f;
    #pragma unroll
    for (int mi = 0; mi < 4; ++mi) {
        #pragma unroll
        for (int ni = 0; ni < 4; ++ni) {
            #pragma unroll
            for (int j = 0; j < 4; ++j) {
                int m = bm + wr * 64 + mi * 16 + ((l >> 4) << 2) + j;
                int n = bn + wc * 64 + ni * 16 + (l & 15);
                if (LAYOUT == 0) {
                    int b = m >> 11, s = m & 2047, h = n >> 6, dk = n & 63;
                    if (z == 2)
                        ((ushort*)O)[(size_t)(b * NHEAD + h) * HSTR + dk * SEQ + s] = f2bf(acc[mi][ni][j]);
                    else
                        ((ushort*)O)[(size_t)(b * NHEAD + h) * HSTR + s * DKD + dk] = f2bf(acc[mi][ni][j] * sc);
                } else {
                    ((float*)O)[(size_t)m * 1024 + n] = acc[mi][ni][j];
                }
            }
        }
    }
}

// ---------------------------------------------------------------------------
// Flash attention, swapped QK^T, exp2-domain softmax, half-tile pipelined:
// QK(A),QK(B) issued; then SM(A)->PV(A) overlap SM(B)->PV(B) (matrix pipe runs
// under softmax VALU). Mask handled by per-block all-ones fast path.
// QBLK=64 (4 waves x 16 q-rows), KVBLK=128 (halves of 64), 2 barriers/tile.
// ---------------------------------------------------------------------------
__global__ __launch_bounds__(256, 4) void attn_fwd(
    const ushort* __restrict__ Q, const ushort* __restrict__ K, const ushort* __restrict__ Vt,
    const int* __restrict__ mask, ushort* __restrict__ ctx)
{
    const int tid = threadIdx.x;
    const int w = tid >> 6, l = tid & 63;
    const int hi = l >> 4, lo = l & 15;
    const int id  = blockIdx.x;
    const int nid = (id & 7) * 128 + (id >> 3);    // XCD-chunked: 4 bh per XCD
    const int bh  = nid >> 5;
    const int q0  = (nid & 31) * 64;
    const int b   = bh >> 4, h = bh & 15;

    __shared__ ushort sm[16384];   // [0,8192): K [128][64] swz; [8192,16384): V [64][128] swz (kphys order)
    __shared__ int mflag;

    // per-block mask scan: uniform fast path when this batch row is all-ones
    if (tid == 0) mflag = 1;
    __syncthreads();
    {
        const int4* mp = (const int4*)(mask + b * SEQ) + tid;
        int4 m0 = mp[0], m1 = mp[256];
        if (!(m0.x && m0.y && m0.z && m0.w && m1.x && m1.y && m1.z && m1.w)) mflag = 0;
    }

    const ushort* Qh = Q  + (size_t)bh * HSTR;
    const ushort* Kh = K  + (size_t)bh * HSTR;
    const ushort* Vh = Vt + (size_t)bh * HSTR;     // [dk][s]

    short8 qf[2];
    #pragma unroll
    for (int kk = 0; kk < 2; ++kk)
        qf[kk] = *(const short8*)(Qh + (size_t)(q0 + w * 16 + lo) * DKD + kk * 32 + hi * 8);

    f32x4 acc_o[4] = {};
    float m_run = -INFINITY, l_run = 0.0f;         // per-lane state for q-row = lo (log2 domain)

    const int kr = tid >> 3;
    const int kc = (tid & 7) << 3;
    const int vr = tid >> 4;
    const int vkpb = (tid & 15) << 4;

    short8  kreg[4];
    short4v vreg0[4], vreg1[4];

    #define LOADT(kt_) {                                                                   \
        _Pragma("unroll")                                                                  \
        for (int i = 0; i < 4; ++i)                                                        \
            kreg[i] = *(const short8*)(Kh + (size_t)((kt_) * 128 + i * 32 + kr) * DKD + kc); \
        _Pragma("unroll")                                                                  \
        for (int i = 0; i < 4; ++i) {                                                      \
            const ushort* vp = Vh + (size_t)(i * 16 + vr) * SEQ + (kt_) * 128 + ((tid >> 2) & 3) * 32 + (tid & 3) * 4; \
            vreg0[i] = *(const short4v*)(vp);                                              \
            vreg1[i] = *(const short4v*)(vp + 16); } }

    #define WRITET() {                                                                     \
        _Pragma("unroll")                                                                  \
        for (int i = 0; i < 4; ++i) {                                                      \
            int r = i * 32 + kr;                                                           \
            *(short8*)((char*)sm + r * 128 + ((kc * 2) ^ ((r & 7) << 4))) = kreg[i]; }     \
        _Pragma("unroll")                                                                  \
        for (int i = 0; i < 4; ++i) {                                                      \
            int r = i * 16 + vr;                                                           \
            char* p = (char*)(sm + 8192) + r * 256 + (vkpb ^ ((r & 7) << 4));              \
            *(short4v*)(p)     = vreg0[i];                                                 \
            *(short4v*)(p + 8) = vreg1[i]; } }

    LOADT(0);
    __syncthreads();                               // mflag ready (and LDS free)
    const bool allones = (mflag != 0);
    WRITET();
    __syncthreads();

    // one half-tile (64 kv) of online softmax + PV; nb = 0 (kv 0-63) or 1 (64-127)
    #define HALF(nb_) {                                                                    \
        f32x4* s = s4 + 4 * (nb_);                                                         \
        if (!allones) {                                                                    \
            const int* mrow = mask + b * SEQ + kt * 128 + (nb_) * 64 + hi * 4;             \
            _Pragma("unroll")                                                              \
            for (int ni = 0; ni < 4; ++ni) {                                               \
                int4 mv = *(const int4*)(mrow + ni * 16);                                  \
                s[ni][0] = mv.x ? s[ni][0] : -1e9f;                                        \
                s[ni][1] = mv.y ? s[ni][1] : -1e9f;                                        \
                s[ni][2] = mv.z ? s[ni][2] : -1e9f;                                        \
                s[ni][3] = mv.w ? s[ni][3] : -1e9f;                                        \
            }                                                                              \
        }                                                                                  \
        float t0 = fmaxf(fmaxf(s[0][0], s[0][1]), fmaxf(s[0][2], s[0][3]));                \
        float t1 = fmaxf(fmaxf(s[1][0], s[1][1]), fmaxf(s[1][2], s[1][3]));                \
        float t2 = fmaxf(fmaxf(s[2][0], s[2][1]), fmaxf(s[2][2], s[2][3]));                \
        float t3 = fmaxf(fmaxf(s[3][0], s[3][1]), fmaxf(s[3][2], s[3][3]));                \
        float t = fmaxf(fmaxf(t0, t1), fmaxf(t2, t3));                                     \
        t = fmaxf(t, __shfl_xor(t, 16));                                                   \
        t = fmaxf(t, __shfl_xor(t, 32));                                                   \
        if (__any(t > m_run)) {                                                            \
            float mnew = fmaxf(m_run, t);                                                  \
            float c = EXP2F(m_run - mnew);                                                 \
            m_run = mnew;                                                                  \
            l_run *= c;                                                                    \
            float cj[4];                                                                   \
            _Pragma("unroll")                                                              \
            for (int j = 0; j < 4; ++j) cj[j] = __shfl(c, (l & 48) | (hi * 4 + j));        \
            _Pragma("unroll")                                                              \
            for (int ni = 0; ni < 4; ++ni)                                                 \
                _Pragma("unroll")                                                          \
                for (int j = 0; j < 4; ++j) acc_o[ni][j] *= cj[j];                         \
        }                                                                                  \
        float rsA = 0.0f;                                                                  \
        _Pragma("unroll")                                                                  \
        for (int ni = 0; ni < 4; ++ni) {                                                   \
            _Pragma("unroll")                                                              \
            for (int j = 0; j < 4; ++j) s[ni][j] = EXP2F(s[ni][j] - m_run);                \
            rsA += (s[ni][0] + s[ni][1]) + (s[ni][2] + s[ni][3]);                          \
        }                                                                                  \
        rsA += __shfl_xor(rsA, 16);                                                        \
        rsA += __shfl_xor(rsA, 32);                                                        \
        l_run += rsA;                                                                      \
        short8 pa[2];                                                                      \
        _Pragma("unroll")                                                                  \
        for (int kk = 0; kk < 2; ++kk) {                                                   \
            U16 cv;                                                                        \
            cv.u[0] = cvtpk(s[2 * kk][0],     s[2 * kk][1]);                               \
            cv.u[1] = cvtpk(s[2 * kk][2],     s[2 * kk][3]);                               \
            cv.u[2] = cvtpk(s[2 * kk + 1][0], s[2 * kk + 1][1]);                           \
            cv.u[3] = cvtpk(s[2 * kk + 1][2], s[2 * kk + 1][3]);                           \
            pa[kk] = cv.s;                                                                 \
        }                                                                                  \
        __builtin_amdgcn_s_setprio(1);                                                     \
        _Pragma("unroll")                                                                  \
        for (int kk = 0; kk < 2; ++kk) {                                                   \
            const int c0 = ((nb_) * 2 + kk) * 32 + hi * 8;                                 \
            _Pragma("unroll")                                                              \
            for (int ni = 0; ni < 4; ++ni) {                                               \
                short8 vf = frag256(sm + 8192, ni * 16 + lo, c0);                          \
                acc_o[ni] = MFMA16(pa[kk], vf, acc_o[ni]);                                 \
            }                                                                              \
        }                                                                                  \
        __builtin_amdgcn_s_setprio(0); }

    #pragma unroll 1
    for (int kt = 0; kt < 16; ++kt) {
        // QK^T both halves: s4[ni] C-layout: kv = ni*16 + hi*4 + j, q = lo
        f32x4 s4[8] = {};
        __builtin_amdgcn_s_setprio(1);
        #pragma unroll
        for (int kk = 0; kk < 2; ++kk) {
            const int c0 = kk * 32 + hi * 8;
            #pragma unroll
            for (int ni = 0; ni < 8; ++ni) {
                short8 kf = frag128(sm, ni * 16 + lo, c0);
                s4[ni] = MFMA16(kf, qf[kk], s4[ni]);
            }
        }
        __builtin_amdgcn_s_setprio(0);

        if (kt < 15) LOADT(kt + 1);

        HALF(0)          // softmax(A) -> PV(A); PV(A) MFMAs run under softmax(B)
        HALF(1)

        __syncthreads();
        if (kt < 15) {
            WRITET();
            __syncthreads();
        }
    }
    #undef HALF
    #undef LOADT
    #undef WRITET

    float inv = 1.0f / l_run;
    float invj[4];
    #pragma unroll
    for (int j = 0; j < 4; ++j)
        invj[j] = __shfl(inv, (l & 48) | (hi * 4 + j));
    #pragma unroll
    for (int ni = 0; ni < 4; ++ni)
        #pragma unroll
        for (int j = 0; j < 4; ++j) {
            int qg = q0 + w * 16 + hi * 4 + j;
            ctx[(size_t)(b * SEQ + qg) * D_MODEL + h * DKD + ni * 16 + lo] = f2bf(acc_o[ni][j] * invj[j]);
        }
}

__global__ void ws_sentinel(float* __restrict__ out, int n, float code) {
    int i = blockIdx.x * blockDim.x + threadIdx.x;
    if (i < n) out[i] = (i == 0) ? code : 0.0f;
}

// ---------------------------------------------------------------------------
extern "C" void kernel_launch(void* const* d_in, const int* in_sizes, int n_in,
                              void* d_out, int out_size, void* d_ws, size_t ws_size,
                              hipStream_t stream) {
    const float* q    = (const float*)d_in[0];
    const float* k    = (const float*)d_in[1];
    const float* v    = (const float*)d_in[2];
    const int*   mask = (const int*)d_in[3];
    const float* wq   = (const float*)d_in[4];
    const float* wk   = (const float*)d_in[5];
    const float* wv   = (const float*)d_in[6];
    const float* wo   = (const float*)d_in[7];
    float* out = (float*)d_out;

    if (ws_size < (size_t)33554432) {
        float code = 100.0f + (float)(ws_size >> 20);
        ws_sentinel<<<(out_size + 255) / 256, 256, 0, stream>>>(out, out_size, code);
        return;
    }

    ushort* ws = (ushort*)d_ws;
    ushort* Qb = ws;                       // [bh][s][dk] bf16 (scaled QSCALE)
    ushort* Kb = ws + 4194304;             // [bh][s][dk]
    ushort* Vb = ws + 8388608;             // [bh][dk][s]  (transposed)
    ushort* Cb = ws + 12582912;            // context [b,s,d] bf16

    dim3 blk(256, 1, 1);
    gemm_nt<0, 0><<<dim3(32, 8, 3), blk, 0, stream>>>(q, k, v, wq, wk, wv, Qb, Kb, Vb);
    attn_fwd<<<dim3(1024, 1, 1), blk, 0, stream>>>(Qb, Kb, Vb, mask, Cb);
    gemm_nt<1, 1><<<dim3(32, 8, 1), blk, 0, stream>>>(Cb, Cb, Cb, wo, wo, wo, out, out, out);
}

// Round 11
// 148.504 us; speedup vs baseline: 1.7495x; 1.2235x over previous
//
#include <hip/hip_runtime.h>
#include <hip/hip_bf16.h>

// MHA forward. f32 inputs (+int32 mask), f32 output; bf16 internal pipeline.
// B=2, S=2048, D_MODEL=1024, H=16, DK=64.
// [cvt weights->bf16] -> [QKV proj GEMM z=3 (Q scaled 0.125*log2e; V transposed
// via LDS-transpose epilogue), T14 prefetch] -> [flash attn] -> [cvt wo] -> [O proj].

typedef short short8  __attribute__((ext_vector_type(8)));
typedef short short4v __attribute__((ext_vector_type(4)));
typedef float f32x4   __attribute__((ext_vector_type(4)));
typedef unsigned int uint4v __attribute__((ext_vector_type(4)));

#define D_MODEL 1024
#define SEQ     2048
#define NHEAD   16
#define DKD     64
#define HSTR    (SEQ * DKD)
#define QSCALE  0.1803368801111204f   // 0.125 * log2(e): exp2-domain softmax
#define EXP2F(x) exp2f(x)

#define MFMA16(a, b, c) __builtin_amdgcn_mfma_f32_16x16x32_bf16((a), (b), (c), 0, 0, 0)

__device__ __forceinline__ ushort f2bf(float f) {
    union { float f; unsigned u; } a; a.f = f;
    unsigned r = a.u + 0x7fffu + ((a.u >> 16) & 1u);
    return (ushort)(r >> 16);
}
__device__ __forceinline__ unsigned cvtpk(float lo, float hi) {
    unsigned r;
    asm("v_cvt_pk_bf16_f32 %0, %1, %2" : "=v"(r) : "v"(lo), "v"(hi));
    return r;
}
union U16 { uint4v u; short8 s; };

__device__ __forceinline__ short8 frag128(const ushort* base, int row, int c0) {
    int cb = (c0 * 2) ^ ((row & 7) << 4);
    return *(const short8*)((const char*)base + row * 128 + cb);
}
__device__ __forceinline__ short8 frag256(const ushort* base, int row, int c0) {
    int cb = (c0 * 2) ^ ((row & 7) << 4);
    return *(const short8*)((const char*)base + row * 256 + cb);
}

// ---------------------------------------------------------------------------
// f32 -> bf16 weight pre-convert: 1M elems per z-slice. grid (512, nz) x 256.
// ---------------------------------------------------------------------------
__global__ __launch_bounds__(256) void cvt_w(
    const float* __restrict__ s0, const float* __restrict__ s1, const float* __restrict__ s2,
    ushort* __restrict__ dst)
{
    const int z = blockIdx.y;
    const float* s = (z == 0) ? s0 : ((z == 1) ? s1 : s2);
    ushort* d = dst + (size_t)z * 1048576;
    const int i = (blockIdx.x * 256 + threadIdx.x) * 8;
    f32x4 a = *(const f32x4*)(s + i);
    f32x4 b = *(const f32x4*)(s + i + 4);
    short8 o;
    #pragma unroll
    for (int u = 0; u < 4; ++u) { o[u] = (short)f2bf(a[u]); o[4 + u] = (short)f2bf(b[u]); }
    *(short8*)(d + i) = o;
}

// ---------------------------------------------------------------------------
// GEMM: C[4096][1024] = A[4096][1024] * W[1024][1024]^T (NT). W is bf16.
// LAYOUT 0 (QKV): z==0 -> head-split bf16 scaled QSCALE (Q); z==1 -> head-split (K);
//                 z==2 -> transposed bf16 [bh][dk][s] via LDS-transpose epilogue (V).
// LAYOUT 1: plain f32 out[m*1024+n] (O-proj).
// T14 async-stage: tile t+1 global->reg loads under tile t's MFMAs.
// ---------------------------------------------------------------------------
template<int LAYOUT, int A_BF16>
__global__ __launch_bounds__(256, 3) void gemm_nt(
    const void* __restrict__ A0, const void* __restrict__ A1, const void* __restrict__ A2,
    const ushort* __restrict__ W0, const ushort* __restrict__ W1, const ushort* __restrict__ W2,
    void* __restrict__ O0, void* __restrict__ O1, void* __restrict__ O2)
{
    const int z = blockIdx.z;
    const void*   A = (z == 0) ? A0 : ((z == 1) ? A1 : A2);
    const ushort* W = (z == 0) ? W0 : ((z == 1) ? W1 : W2);
    void* O         = (z == 0) ? O0 : ((z == 1) ? O1 : O2);

    const int bm = blockIdx.x * 128;
    const int bn = blockIdx.y * 128;
    const int tid = threadIdx.x;
    const int w = tid >> 6, l = tid & 63;
    const int wr = w >> 1, wc = w & 1;

    __shared__ ushort sm[16384];

    f32x4 acc[4][4] = {};
    short8 areg[4], wreg[4];
    const int srow = tid >> 3;
    const int sc8  = (tid & 7) << 3;
    const int scb  = (sc8 * 2);

    #define GLOADT(t_) {                                                                    \
        _Pragma("unroll")                                                                   \
        for (int i = 0; i < 4; ++i) {                                                       \
            int row = i * 32 + srow;                                                        \
            if (A_BF16) {                                                                   \
                areg[i] = *(const short8*)((const ushort*)A + (size_t)(bm + row) * 1024 + (t_) * 64 + sc8); \
            } else {                                                                        \
                const float* ap = (const float*)A + (size_t)(bm + row) * 1024 + (t_) * 64 + sc8; \
                f32x4 x0 = *(const f32x4*)ap, x1 = *(const f32x4*)(ap + 4);                 \
                _Pragma("unroll")                                                           \
                for (int u = 0; u < 4; ++u) { areg[i][u] = (short)f2bf(x0[u]); areg[i][4 + u] = (short)f2bf(x1[u]); } \
            }                                                                               \
            wreg[i] = *(const short8*)(W + (size_t)(bn + row) * 1024 + (t_) * 64 + sc8);    \
        } }

    #define GWRITET() {                                                                     \
        _Pragma("unroll")                                                                   \
        for (int i = 0; i < 4; ++i) {                                                       \
            int row = i * 32 + srow;                                                        \
            int cb  = scb ^ ((row & 7) << 4);                                               \
            *(short8*)((char*)sm + row * 128 + cb) = areg[i];                               \
            *(short8*)((char*)(sm + 8192) + row * 128 + cb) = wreg[i];                      \
        } }

    GLOADT(0);
    #pragma unroll 1
    for (int t = 0; t < 16; ++t) {
        GWRITET();
        __syncthreads();
        if (t < 15) GLOADT(t + 1);

        #pragma unroll
        for (int kk = 0; kk < 2; ++kk) {
            const int c0 = kk * 32 + ((l >> 4) << 3);
            short8 af[4], bf[4];
            #pragma unroll
            for (int mi = 0; mi < 4; ++mi)
                af[mi] = frag128(sm, wr * 64 + mi * 16 + (l & 15), c0);
            #pragma unroll
            for (int ni = 0; ni < 4; ++ni)
                bf[ni] = frag128(sm + 8192, wc * 64 + ni * 16 + (l & 15), c0);
            #pragma unroll
            for (int mi = 0; mi < 4; ++mi)
                #pragma unroll
                for (int ni = 0; ni < 4; ++ni)
                    acc[mi][ni] = MFMA16(af[mi], bf[ni], acc[mi][ni]);
        }
        __syncthreads();
    }
    #undef GLOADT
    #undef GWRITET

    if (LAYOUT == 0 && z == 2) {
        // V epilogue: transpose in LDS, write [bh][dk][s] with 128B-contiguous runs.
        // (loop ended with __syncthreads(): sm is free to overwrite)
        #pragma unroll
        for (int mi = 0; mi < 4; ++mi) {
            #pragma unroll
            for (int ni = 0; ni < 4; ++ni) {
                int n_l = wc * 64 + ni * 16 + (l & 15);
                int m0  = wr * 64 + mi * 16 + ((l >> 4) << 2);
                short4v v4;
                #pragma unroll
                for (int j = 0; j < 4; ++j) v4[j] = (short)f2bf(acc[mi][ni][j]);
                *(short4v*)((char*)sm + n_l * 256 + ((m0 * 2) ^ ((n_l & 7) << 4))) = v4;
            }
        }
        __syncthreads();
        const int row = tid >> 1, half = tid & 1;
        const int n_g = bn + row;
        const int bb  = bm >> 11;
        ushort* Op = (ushort*)O + (size_t)(bb * NHEAD + (n_g >> 6)) * HSTR
                     + (size_t)(n_g & 63) * SEQ + (bm & 2047) + half * 64;
        #pragma unroll
        for (int u = 0; u < 8; ++u) {
            short8 c = *(const short8*)((char*)sm + row * 256
                        + (((half * 64 + u * 8) * 2) ^ ((row & 7) << 4)));
            *(short8*)(Op + u * 8) = c;
        }
        return;
    }

    const float sc = (LAYOUT == 0 && z == 0) ? QSCALE : 1.0f;
    #pragma unroll
    for (int mi = 0; mi < 4; ++mi) {
        #pragma unroll
        for (int ni = 0; ni < 4; ++ni) {
            #pragma unroll
            for (int j = 0; j < 4; ++j) {
                int m = bm + wr * 64 + mi * 16 + ((l >> 4) << 2) + j;
                int n = bn + wc * 64 + ni * 16 + (l & 15);
                if (LAYOUT == 0) {
                    int b = m >> 11, s = m & 2047, h = n >> 6, dk = n & 63;
                    ((ushort*)O)[(size_t)(b * NHEAD + h) * HSTR + s * DKD + dk] = f2bf(acc[mi][ni][j] * sc);
                } else {
                    ((float*)O)[(size_t)m * 1024 + n] = acc[mi][ni][j];
                }
            }
        }
    }
}

// ---------------------------------------------------------------------------
// Flash attention, swapped QK^T, exp2-domain softmax, half-tile pipelined.
// QBLK=64 (4 waves x 16 q-rows), KVBLK=128 (halves of 64), 2 barriers/tile.
// ---------------------------------------------------------------------------
__global__ __launch_bounds__(256, 4) void attn_fwd(
    const ushort* __restrict__ Q, const ushort* __restrict__ K, const ushort* __restrict__ Vt,
    const int* __restrict__ mask, ushort* __restrict__ ctx)
{
    const int tid = threadIdx.x;
    const int w = tid >> 6, l = tid & 63;
    const int hi = l >> 4, lo = l & 15;
    const int id  = blockIdx.x;
    const int nid = (id & 7) * 128 + (id >> 3);    // XCD-chunked: 4 bh per XCD
    const int bh  = nid >> 5;
    const int q0  = (nid & 31) * 64;
    const int b   = bh >> 4, h = bh & 15;

    __shared__ ushort sm[16384];   // [0,8192): K [128][64] swz; [8192,16384): V [64][128] swz (kphys order)
    __shared__ int mflag;

    if (tid == 0) mflag = 1;
    __syncthreads();
    {
        const int4* mp = (const int4*)(mask + b * SEQ) + tid;
        int4 m0 = mp[0], m1 = mp[256];
        if (!(m0.x && m0.y && m0.z && m0.w && m1.x && m1.y && m1.z && m1.w)) mflag = 0;
    }

    const ushort* Qh = Q  + (size_t)bh * HSTR;
    const ushort* Kh = K  + (size_t)bh * HSTR;
    const ushort* Vh = Vt + (size_t)bh * HSTR;     // [dk][s]

    short8 qf[2];
    #pragma unroll
    for (int kk = 0; kk < 2; ++kk)
        qf[kk] = *(const short8*)(Qh + (size_t)(q0 + w * 16 + lo) * DKD + kk * 32 + hi * 8);

    f32x4 acc_o[4] = {};
    float m_run = -INFINITY, l_run = 0.0f;

    const int kr = tid >> 3;
    const int kc = (tid & 7) << 3;
    const int vr = tid >> 4;
    const int vkpb = (tid & 15) << 4;

    short8  kreg[4];
    short4v vreg0[4], vreg1[4];

    #define LOADT(kt_) {                                                                   \
        _Pragma("unroll")                                                                  \
        for (int i = 0; i < 4; ++i)                                                        \
            kreg[i] = *(const short8*)(Kh + (size_t)((kt_) * 128 + i * 32 + kr) * DKD + kc); \
        _Pragma("unroll")                                                                  \
        for (int i = 0; i < 4; ++i) {                                                      \
            const ushort* vp = Vh + (size_t)(i * 16 + vr) * SEQ + (kt_) * 128 + ((tid >> 2) & 3) * 32 + (tid & 3) * 4; \
            vreg0[i] = *(const short4v*)(vp);                                              \
            vreg1[i] = *(const short4v*)(vp + 16); } }

    #define WRITET() {                                                                     \
        _Pragma("unroll")                                                                  \
        for (int i = 0; i < 4; ++i) {                                                      \
            int r = i * 32 + kr;                                                           \
            *(short8*)((char*)sm + r * 128 + ((kc * 2) ^ ((r & 7) << 4))) = kreg[i]; }     \
        _Pragma("unroll")                                                                  \
        for (int i = 0; i < 4; ++i) {                                                      \
            int r = i * 16 + vr;                                                           \
            char* p = (char*)(sm + 8192) + r * 256 + (vkpb ^ ((r & 7) << 4));              \
            *(short4v*)(p)     = vreg0[i];                                                 \
            *(short4v*)(p + 8) = vreg1[i]; } }

    LOADT(0);
    __syncthreads();
    const bool allones = (mflag != 0);
    WRITET();
    __syncthreads();

    #define HALF(nb_) {                                                                    \
        f32x4* s = s4 + 4 * (nb_);                                                         \
        if (!allones) {                                                                    \
            const int* mrow = mask + b * SEQ + kt * 128 + (nb_) * 64 + hi * 4;             \
            _Pragma("unroll")                                                              \
            for (int ni = 0; ni < 4; ++ni) {                                               \
                int4 mv = *(const int4*)(mrow + ni * 16);                                  \
                s[ni][0] = mv.x ? s[ni][0] : -1e9f;                                        \
                s[ni][1] = mv.y ? s[ni][1] : -1e9f;                                        \
                s[ni][2] = mv.z ? s[ni][2] : -1e9f;                                        \
                s[ni][3] = mv.w ? s[ni][3] : -1e9f;                                        \
            }                                                                              \
        }                                                                                  \
        float t0 = fmaxf(fmaxf(s[0][0], s[0][1]), fmaxf(s[0][2], s[0][3]));                \
        float t1 = fmaxf(fmaxf(s[1][0], s[1][1]), fmaxf(s[1][2], s[1][3]));                \
        float t2 = fmaxf(fmaxf(s[2][0], s[2][1]), fmaxf(s[2][2], s[2][3]));                \
        float t3 = fmaxf(fmaxf(s[3][0], s[3][1]), fmaxf(s[3][2], s[3][3]));                \
        float t = fmaxf(fmaxf(t0, t1), fmaxf(t2, t3));                                     \
        t = fmaxf(t, __shfl_xor(t, 16));                                                   \
        t = fmaxf(t, __shfl_xor(t, 32));                                                   \
        if (__any(t > m_run)) {                                                            \
            float mnew = fmaxf(m_run, t);                                                  \
            float c = EXP2F(m_run - mnew);                                                 \
            m_run = mnew;                                                                  \
            l_run *= c;                                                                    \
            float cj[4];                                                                   \
            _Pragma("unroll")                                                              \
            for (int j = 0; j < 4; ++j) cj[j] = __shfl(c, (l & 48) | (hi * 4 + j));        \
            _Pragma("unroll")                                                              \
            for (int ni = 0; ni < 4; ++ni)                                                 \
                _Pragma("unroll")                                                          \
                for (int j = 0; j < 4; ++j) acc_o[ni][j] *= cj[j];                         \
        }                                                                                  \
        float rsA = 0.0f;                                                                  \
        _Pragma("unroll")                                                                  \
        for (int ni = 0; ni < 4; ++ni) {                                                   \
            _Pragma("unroll")                                                              \
            for (int j = 0; j < 4; ++j) s[ni][j] = EXP2F(s[ni][j] - m_run);                \
            rsA += (s[ni][0] + s[ni][1]) + (s[ni][2] + s[ni][3]);                          \
        }                                                                                  \
        rsA += __shfl_xor(rsA, 16);                                                        \
        rsA += __shfl_xor(rsA, 32);                                                        \
        l_run += rsA;                                                                      \
        short8 pa[2];                                                                      \
        _Pragma("unroll")                                                                  \
        for (int kk = 0; kk < 2; ++kk) {                                                   \
            U16 cv;                                                                        \
            cv.u[0] = cvtpk(s[2 * kk][0],     s[2 * kk][1]);                               \
            cv.u[1] = cvtpk(s[2 * kk][2],     s[2 * kk][3]);                               \
            cv.u[2] = cvtpk(s[2 * kk + 1][0], s[2 * kk + 1][1]);                           \
            cv.u[3] = cvtpk(s[2 * kk + 1][2], s[2 * kk + 1][3]);                           \
            pa[kk] = cv.s;                                                                 \
        }                                                                                  \
        __builtin_amdgcn_s_setprio(1);                                                     \
        _Pragma("unroll")                                                                  \
        for (int kk = 0; kk < 2; ++kk) {                                                   \
            const int c0 = ((nb_) * 2 + kk) * 32 + hi * 8;                                 \
            _Pragma("unroll")                                                              \
            for (int ni = 0; ni < 4; ++ni) {                                               \
                short8 vf = frag256(sm + 8192, ni * 16 + lo, c0);                          \
                acc_o[ni] = MFMA16(pa[kk], vf, acc_o[ni]);                                 \
            }                                                                              \
        }                                                                                  \
        __builtin_amdgcn_s_setprio(0); }

    #pragma unroll 1
    for (int kt = 0; kt < 16; ++kt) {
        f32x4 s4[8] = {};
        __builtin_amdgcn_s_setprio(1);
        #pragma unroll
        for (int kk = 0; kk < 2; ++kk) {
            const int c0 = kk * 32 + hi * 8;
            #pragma unroll
            for (int ni = 0; ni < 8; ++ni) {
                short8 kf = frag128(sm, ni * 16 + lo, c0);
                s4[ni] = MFMA16(kf, qf[kk], s4[ni]);
            }
        }
        __builtin_amdgcn_s_setprio(0);

        if (kt < 15) LOADT(kt + 1);

        HALF(0)
        HALF(1)

        __syncthreads();
        if (kt < 15) {
            WRITET();
            __syncthreads();
        }
    }
    #undef HALF
    #undef LOADT
    #undef WRITET

    float inv = 1.0f / l_run;
    float invj[4];
    #pragma unroll
    for (int j = 0; j < 4; ++j)
        invj[j] = __shfl(inv, (l & 48) | (hi * 4 + j));
    #pragma unroll
    for (int ni = 0; ni < 4; ++ni)
        #pragma unroll
        for (int j = 0; j < 4; ++j) {
            int qg = q0 + w * 16 + hi * 4 + j;
            ctx[(size_t)(b * SEQ + qg) * D_MODEL + h * DKD + ni * 16 + lo] = f2bf(acc_o[ni][j] * invj[j]);
        }
}

__global__ void ws_sentinel(float* __restrict__ out, int n, float code) {
    int i = blockIdx.x * blockDim.x + threadIdx.x;
    if (i < n) out[i] = (i == 0) ? code : 0.0f;
}

// ---------------------------------------------------------------------------
extern "C" void kernel_launch(void* const* d_in, const int* in_sizes, int n_in,
                              void* d_out, int out_size, void* d_ws, size_t ws_size,
                              hipStream_t stream) {
    const float* q    = (const float*)d_in[0];
    const float* k    = (const float*)d_in[1];
    const float* v    = (const float*)d_in[2];
    const int*   mask = (const int*)d_in[3];
    const float* wq   = (const float*)d_in[4];
    const float* wk   = (const float*)d_in[5];
    const float* wv   = (const float*)d_in[6];
    const float* wo   = (const float*)d_in[7];
    float* out = (float*)d_out;

    if (ws_size < (size_t)33554432) {
        float code = 100.0f + (float)(ws_size >> 20);
        ws_sentinel<<<(out_size + 255) / 256, 256, 0, stream>>>(out, out_size, code);
        return;
    }

    ushort* ws = (ushort*)d_ws;
    ushort* Qb = ws;                       // [bh][s][dk] bf16 (scaled QSCALE); later: wo bf16
    ushort* Kb = ws + 4194304;             // [bh][s][dk]
    ushort* Vb = ws + 8388608;             // [bh][dk][s]  (transposed)
    ushort* Cb = ws + 12582912;            // first: wq/wk/wv bf16; then context [b,s,d] bf16

    dim3 blk(256, 1, 1);
    // wq,wk,wv -> bf16 in Cb (Cb is dead until attn writes ctx)
    cvt_w<<<dim3(512, 3), blk, 0, stream>>>(wq, wk, wv, Cb);
    gemm_nt<0, 0><<<dim3(32, 8, 3), blk, 0, stream>>>(
        q, k, v, Cb, Cb + 1048576, Cb + 2097152, Qb, Kb, Vb);
    attn_fwd<<<dim3(1024, 1, 1), blk, 0, stream>>>(Qb, Kb, Vb, mask, Cb);
    // wo -> bf16 in Qb (Qb is dead after attn)
    cvt_w<<<dim3(512, 1), blk, 0, stream>>>(wo, wo, wo, Qb);
    gemm_nt<1, 1><<<dim3(32, 8, 1), blk, 0, stream>>>(
        Cb, Cb, Cb, Qb, Qb, Qb, out, out, out);
}

// Round 12
// 135.549 us; speedup vs baseline: 1.9168x; 1.0956x over previous
//
#include <hip/hip_runtime.h>
#include <hip/hip_bf16.h>

// MHA forward. f32 inputs (+int32 mask), f32 output; bf16 internal pipeline.
// B=2, S=2048, D_MODEL=1024, H=16, DK=64.
// [cvt weights->bf16] -> [QKV proj GEMM z=3 (Q scaled 0.125*log2e; V transposed
// via LDS-transpose epilogue), T14 prefetch] -> [flash attn: 8-wave QBLK=128,
// LDS dbuf 1-barrier/tile, defer-max] -> [cvt wo] -> [O proj].

typedef short short8  __attribute__((ext_vector_type(8)));
typedef short short4v __attribute__((ext_vector_type(4)));
typedef float f32x4   __attribute__((ext_vector_type(4)));
typedef unsigned int uint4v __attribute__((ext_vector_type(4)));

#define D_MODEL 1024
#define SEQ     2048
#define NHEAD   16
#define DKD     64
#define HSTR    (SEQ * DKD)
#define QSCALE  0.1803368801111204f   // 0.125 * log2(e): exp2-domain softmax
#define EXP2F(x) exp2f(x)

#define MFMA16(a, b, c) __builtin_amdgcn_mfma_f32_16x16x32_bf16((a), (b), (c), 0, 0, 0)

__device__ __forceinline__ ushort f2bf(float f) {
    union { float f; unsigned u; } a; a.f = f;
    unsigned r = a.u + 0x7fffu + ((a.u >> 16) & 1u);
    return (ushort)(r >> 16);
}
__device__ __forceinline__ unsigned cvtpk(float lo, float hi) {
    unsigned r;
    asm("v_cvt_pk_bf16_f32 %0, %1, %2" : "=v"(r) : "v"(lo), "v"(hi));
    return r;
}
union U16 { uint4v u; short8 s; };

__device__ __forceinline__ short8 frag128(const ushort* base, int row, int c0) {
    int cb = (c0 * 2) ^ ((row & 7) << 4);
    return *(const short8*)((const char*)base + row * 128 + cb);
}
__device__ __forceinline__ short8 frag256(const ushort* base, int row, int c0) {
    int cb = (c0 * 2) ^ ((row & 7) << 4);
    return *(const short8*)((const char*)base + row * 256 + cb);
}

// ---------------------------------------------------------------------------
// f32 -> bf16 weight pre-convert: 1M elems per z-slice. grid (512, nz) x 256.
// ---------------------------------------------------------------------------
__global__ __launch_bounds__(256) void cvt_w(
    const float* __restrict__ s0, const float* __restrict__ s1, const float* __restrict__ s2,
    ushort* __restrict__ dst)
{
    const int z = blockIdx.y;
    const float* s = (z == 0) ? s0 : ((z == 1) ? s1 : s2);
    ushort* d = dst + (size_t)z * 1048576;
    const int i = (blockIdx.x * 256 + threadIdx.x) * 8;
    f32x4 a = *(const f32x4*)(s + i);
    f32x4 b = *(const f32x4*)(s + i + 4);
    short8 o;
    #pragma unroll
    for (int u = 0; u < 4; ++u) { o[u] = (short)f2bf(a[u]); o[4 + u] = (short)f2bf(b[u]); }
    *(short8*)(d + i) = o;
}

// ---------------------------------------------------------------------------
// GEMM: C[4096][1024] = A[4096][1024] * W[1024][1024]^T (NT). W is bf16.
// LAYOUT 0 (QKV): z==0 -> head-split bf16 scaled QSCALE (Q); z==1 -> head-split (K);
//                 z==2 -> transposed bf16 [bh][dk][s] via LDS-transpose epilogue (V).
// LAYOUT 1: plain f32 out[m*1024+n] (O-proj).
// ---------------------------------------------------------------------------
template<int LAYOUT, int A_BF16>
__global__ __launch_bounds__(256, 3) void gemm_nt(
    const void* __restrict__ A0, const void* __restrict__ A1, const void* __restrict__ A2,
    const ushort* __restrict__ W0, const ushort* __restrict__ W1, const ushort* __restrict__ W2,
    void* __restrict__ O0, void* __restrict__ O1, void* __restrict__ O2)
{
    const int z = blockIdx.z;
    const void*   A = (z == 0) ? A0 : ((z == 1) ? A1 : A2);
    const ushort* W = (z == 0) ? W0 : ((z == 1) ? W1 : W2);
    void* O         = (z == 0) ? O0 : ((z == 1) ? O1 : O2);

    const int bm = blockIdx.x * 128;
    const int bn = blockIdx.y * 128;
    const int tid = threadIdx.x;
    const int w = tid >> 6, l = tid & 63;
    const int wr = w >> 1, wc = w & 1;

    __shared__ ushort sm[16384];

    f32x4 acc[4][4] = {};
    short8 areg[4], wreg[4];
    const int srow = tid >> 3;
    const int sc8  = (tid & 7) << 3;
    const int scb  = (sc8 * 2);

    #define GLOADT(t_) {                                                                    \
        _Pragma("unroll")                                                                   \
        for (int i = 0; i < 4; ++i) {                                                       \
            int row = i * 32 + srow;                                                        \
            if (A_BF16) {                                                                   \
                areg[i] = *(const short8*)((const ushort*)A + (size_t)(bm + row) * 1024 + (t_) * 64 + sc8); \
            } else {                                                                        \
                const float* ap = (const float*)A + (size_t)(bm + row) * 1024 + (t_) * 64 + sc8; \
                f32x4 x0 = *(const f32x4*)ap, x1 = *(const f32x4*)(ap + 4);                 \
                _Pragma("unroll")                                                           \
                for (int u = 0; u < 4; ++u) { areg[i][u] = (short)f2bf(x0[u]); areg[i][4 + u] = (short)f2bf(x1[u]); } \
            }                                                                               \
            wreg[i] = *(const short8*)(W + (size_t)(bn + row) * 1024 + (t_) * 64 + sc8);    \
        } }

    #define GWRITET() {                                                                     \
        _Pragma("unroll")                                                                   \
        for (int i = 0; i < 4; ++i) {                                                       \
            int row = i * 32 + srow;                                                        \
            int cb  = scb ^ ((row & 7) << 4);                                               \
            *(short8*)((char*)sm + row * 128 + cb) = areg[i];                               \
            *(short8*)((char*)(sm + 8192) + row * 128 + cb) = wreg[i];                      \
        } }

    GLOADT(0);
    #pragma unroll 1
    for (int t = 0; t < 16; ++t) {
        GWRITET();
        __syncthreads();
        if (t < 15) GLOADT(t + 1);

        #pragma unroll
        for (int kk = 0; kk < 2; ++kk) {
            const int c0 = kk * 32 + ((l >> 4) << 3);
            short8 af[4], bf[4];
            #pragma unroll
            for (int mi = 0; mi < 4; ++mi)
                af[mi] = frag128(sm, wr * 64 + mi * 16 + (l & 15), c0);
            #pragma unroll
            for (int ni = 0; ni < 4; ++ni)
                bf[ni] = frag128(sm + 8192, wc * 64 + ni * 16 + (l & 15), c0);
            #pragma unroll
            for (int mi = 0; mi < 4; ++mi)
                #pragma unroll
                for (int ni = 0; ni < 4; ++ni)
                    acc[mi][ni] = MFMA16(af[mi], bf[ni], acc[mi][ni]);
        }
        __syncthreads();
    }
    #undef GLOADT
    #undef GWRITET

    if (LAYOUT == 0 && z == 2) {
        // V epilogue: transpose in LDS, write [bh][dk][s] with 128B-contiguous runs.
        #pragma unroll
        for (int mi = 0; mi < 4; ++mi) {
            #pragma unroll
            for (int ni = 0; ni < 4; ++ni) {
                int n_l = wc * 64 + ni * 16 + (l & 15);
                int m0  = wr * 64 + mi * 16 + ((l >> 4) << 2);
                short4v v4;
                #pragma unroll
                for (int j = 0; j < 4; ++j) v4[j] = (short)f2bf(acc[mi][ni][j]);
                *(short4v*)((char*)sm + n_l * 256 + ((m0 * 2) ^ ((n_l & 7) << 4))) = v4;
            }
        }
        __syncthreads();
        const int row = tid >> 1, half = tid & 1;
        const int n_g = bn + row;
        const int bb  = bm >> 11;
        ushort* Op = (ushort*)O + (size_t)(bb * NHEAD + (n_g >> 6)) * HSTR
                     + (size_t)(n_g & 63) * SEQ + (bm & 2047) + half * 64;
        #pragma unroll
        for (int u = 0; u < 8; ++u) {
            short8 c = *(const short8*)((char*)sm + row * 256
                        + (((half * 64 + u * 8) * 2) ^ ((row & 7) << 4)));
            *(short8*)(Op + u * 8) = c;
        }
        return;
    }

    const float sc = (LAYOUT == 0 && z == 0) ? QSCALE : 1.0f;
    #pragma unroll
    for (int mi = 0; mi < 4; ++mi) {
        #pragma unroll
        for (int ni = 0; ni < 4; ++ni) {
            #pragma unroll
            for (int j = 0; j < 4; ++j) {
                int m = bm + wr * 64 + mi * 16 + ((l >> 4) << 2) + j;
                int n = bn + wc * 64 + ni * 16 + (l & 15);
                if (LAYOUT == 0) {
                    int b = m >> 11, s = m & 2047, h = n >> 6, dk = n & 63;
                    ((ushort*)O)[(size_t)(b * NHEAD + h) * HSTR + s * DKD + dk] = f2bf(acc[mi][ni][j] * sc);
                } else {
                    ((float*)O)[(size_t)m * 1024 + n] = acc[mi][ni][j];
                }
            }
        }
    }
}

// ---------------------------------------------------------------------------
// Flash attention. 512 thr = 8 waves, QBLK=128 (16 q-rows/wave), KVBLK=128,
// LDS double-buffer (64 KB) -> ONE barrier per tile. Swapped QK^T, exp2-domain
// in-register softmax, defer-max THR=8, zero-C MFMA s4 init.
// Grid 512 (XCD-chunked, 2 bh per XCD).
// ---------------------------------------------------------------------------
__global__ __launch_bounds__(512, 4) void attn_fwd(
    const ushort* __restrict__ Q, const ushort* __restrict__ K, const ushort* __restrict__ Vt,
    const int* __restrict__ mask, ushort* __restrict__ ctx)
{
    const int tid = threadIdx.x;
    const int w = tid >> 6, l = tid & 63;
    const int hi = l >> 4, lo = l & 15;
    const int id  = blockIdx.x;
    const int nid = (id & 7) * 64 + (id >> 3);     // 8 XCDs x 64 blocks
    const int bh  = nid >> 4;
    const int q0  = (nid & 15) * 128;
    const int b   = bh >> 4, h = bh & 15;

    __shared__ ushort sm[2][16384];  // per buf: K [128][64] swz @0; V [64][128] swz @8192
    __shared__ int mflag;

    if (tid == 0) mflag = 1;
    __syncthreads();
    {
        int4 m0 = ((const int4*)(mask + b * SEQ))[tid];
        if (!(m0.x && m0.y && m0.z && m0.w)) mflag = 0;
    }

    const ushort* Qh = Q  + (size_t)bh * HSTR;
    const ushort* Kh = K  + (size_t)bh * HSTR;
    const ushort* Vh = Vt + (size_t)bh * HSTR;     // [dk][s]

    short8 qf[2];
    #pragma unroll
    for (int kk = 0; kk < 2; ++kk)
        qf[kk] = *(const short8*)(Qh + (size_t)(q0 + w * 16 + lo) * DKD + kk * 32 + hi * 8);

    f32x4 acc_o[4] = {};
    float m_run = -INFINITY, l_run = 0.0f;

    const int kr = tid >> 3;               // 0..63
    const int kc = (tid & 7) << 3;
    const int vr = tid >> 4;               // 0..31
    const int vkpb = (tid & 15) << 4;

    short8  kreg[2];
    short4v vreg0[2], vreg1[2];

    #define LOADT(kt_) {                                                                   \
        _Pragma("unroll")                                                                  \
        for (int i = 0; i < 2; ++i)                                                        \
            kreg[i] = *(const short8*)(Kh + (size_t)((kt_) * 128 + i * 64 + kr) * DKD + kc); \
        _Pragma("unroll")                                                                  \
        for (int i = 0; i < 2; ++i) {                                                      \
            const ushort* vp = Vh + (size_t)(i * 32 + vr) * SEQ + (kt_) * 128 + ((tid >> 2) & 3) * 32 + (tid & 3) * 4; \
            vreg0[i] = *(const short4v*)(vp);                                              \
            vreg1[i] = *(const short4v*)(vp + 16); } }

    #define WRITET(buf_) {                                                                 \
        _Pragma("unroll")                                                                  \
        for (int i = 0; i < 2; ++i) {                                                      \
            int r = i * 64 + kr;                                                           \
            *(short8*)((char*)sm[buf_] + r * 128 + ((kc * 2) ^ ((r & 7) << 4))) = kreg[i]; } \
        _Pragma("unroll")                                                                  \
        for (int i = 0; i < 2; ++i) {                                                      \
            int r = i * 32 + vr;                                                           \
            char* p = (char*)(sm[buf_] + 8192) + r * 256 + (vkpb ^ ((r & 7) << 4));        \
            *(short4v*)(p)     = vreg0[i];                                                 \
            *(short4v*)(p + 8) = vreg1[i]; } }

    LOADT(0); WRITET(0);
    __syncthreads();                       // buf0 staged + mflag final
    const bool allones = (mflag != 0);
    const f32x4 zf = {};

    #define HALF(nb_) {                                                                    \
        f32x4* s = s4 + 4 * (nb_);                                                         \
        if (!allones) {                                                                    \
            const int* mrow = mask + b * SEQ + kt * 128 + (nb_) * 64 + hi * 4;             \
            _Pragma("unroll")                                                              \
            for (int ni = 0; ni < 4; ++ni) {                                               \
                int4 mv = *(const int4*)(mrow + ni * 16);                                  \
                s[ni][0] = mv.x ? s[ni][0] : -1e9f;                                        \
                s[ni][1] = mv.y ? s[ni][1] : -1e9f;                                        \
                s[ni][2] = mv.z ? s[ni][2] : -1e9f;                                        \
                s[ni][3] = mv.w ? s[ni][3] : -1e9f;                                        \
            }                                                                              \
        }                                                                                  \
        float t0 = fmaxf(fmaxf(s[0][0], s[0][1]), fmaxf(s[0][2], s[0][3]));                \
        float t1 = fmaxf(fmaxf(s[1][0], s[1][1]), fmaxf(s[1][2], s[1][3]));                \
        float t2 = fmaxf(fmaxf(s[2][0], s[2][1]), fmaxf(s[2][2], s[2][3]));                \
        float t3 = fmaxf(fmaxf(s[3][0], s[3][1]), fmaxf(s[3][2], s[3][3]));                \
        float t = fmaxf(fmaxf(t0, t1), fmaxf(t2, t3));                                     \
        t = fmaxf(t, __shfl_xor(t, 16));                                                   \
        t = fmaxf(t, __shfl_xor(t, 32));                                                   \
        if (!__all(t <= m_run + 8.0f)) {   /* defer-max: rescale only on real growth */    \
            float mnew = fmaxf(m_run, t);                                                  \
            float c = EXP2F(m_run - mnew);                                                 \
            m_run = mnew;                                                                  \
            l_run *= c;                                                                    \
            float cj[4];                                                                   \
            _Pragma("unroll")                                                              \
            for (int j = 0; j < 4; ++j) cj[j] = __shfl(c, (l & 48) | (hi * 4 + j));        \
            _Pragma("unroll")                                                              \
            for (int ni = 0; ni < 4; ++ni)                                                 \
                _Pragma("unroll")                                                          \
                for (int j = 0; j < 4; ++j) acc_o[ni][j] *= cj[j];                         \
        }                                                                                  \
        float rsA = 0.0f;                                                                  \
        _Pragma("unroll")                                                                  \
        for (int ni = 0; ni < 4; ++ni) {                                                   \
            _Pragma("unroll")                                                              \
            for (int j = 0; j < 4; ++j) s[ni][j] = EXP2F(s[ni][j] - m_run);                \
            rsA += (s[ni][0] + s[ni][1]) + (s[ni][2] + s[ni][3]);                          \
        }                                                                                  \
        rsA += __shfl_xor(rsA, 16);                                                        \
        rsA += __shfl_xor(rsA, 32);                                                        \
        l_run += rsA;                                                                      \
        short8 pa[2];                                                                      \
        _Pragma("unroll")                                                                  \
        for (int kk = 0; kk < 2; ++kk) {                                                   \
            U16 cv;                                                                        \
            cv.u[0] = cvtpk(s[2 * kk][0],     s[2 * kk][1]);                               \
            cv.u[1] = cvtpk(s[2 * kk][2],     s[2 * kk][3]);                               \
            cv.u[2] = cvtpk(s[2 * kk + 1][0], s[2 * kk + 1][1]);                           \
            cv.u[3] = cvtpk(s[2 * kk + 1][2], s[2 * kk + 1][3]);                           \
            pa[kk] = cv.s;                                                                 \
        }                                                                                  \
        __builtin_amdgcn_s_setprio(1);                                                     \
        _Pragma("unroll")                                                                  \
        for (int kk = 0; kk < 2; ++kk) {                                                   \
            const int c0 = ((nb_) * 2 + kk) * 32 + hi * 8;                                 \
            _Pragma("unroll")                                                              \
            for (int ni = 0; ni < 4; ++ni) {                                               \
                short8 vf = frag256(vb, ni * 16 + lo, c0);                                 \
                acc_o[ni] = MFMA16(pa[kk], vf, acc_o[ni]);                                 \
            }                                                                              \
        }                                                                                  \
        __builtin_amdgcn_s_setprio(0); }

    #pragma unroll 1
    for (int kt = 0; kt < 16; ++kt) {
        const int cur = kt & 1;
        const ushort* kb = sm[cur];
        const ushort* vb = sm[cur] + 8192;

        if (kt < 15) LOADT(kt + 1);        // global->regs, lands under QK^T+SM(A)

        // QK^T: s4[ni] C-layout: kv = ni*16 + hi*4 + j, q = lo. Zero-C init.
        f32x4 s4[8];
        __builtin_amdgcn_s_setprio(1);
        #pragma unroll
        for (int ni = 0; ni < 8; ++ni)
            s4[ni] = MFMA16(frag128(kb, ni * 16 + lo, hi * 8), qf[0], zf);
        #pragma unroll
        for (int ni = 0; ni < 8; ++ni)
            s4[ni] = MFMA16(frag128(kb, ni * 16 + lo, 32 + hi * 8), qf[1], s4[ni]);
        __builtin_amdgcn_s_setprio(0);

        HALF(0)
        if (kt < 15) WRITET(cur ^ 1);      // regs->other buffer (free: tile kt-1's reads done)
        HALF(1)

        __syncthreads();                   // single barrier: buf[cur] reads + buf[cur^1] writes done
    }
    #undef HALF
    #undef LOADT
    #undef WRITET

    float inv = 1.0f / l_run;
    float invj[4];
    #pragma unroll
    for (int j = 0; j < 4; ++j)
        invj[j] = __shfl(inv, (l & 48) | (hi * 4 + j));
    #pragma unroll
    for (int ni = 0; ni < 4; ++ni)
        #pragma unroll
        for (int j = 0; j < 4; ++j) {
            int qg = q0 + w * 16 + hi * 4 + j;
            ctx[(size_t)(b * SEQ + qg) * D_MODEL + h * DKD + ni * 16 + lo] = f2bf(acc_o[ni][j] * invj[j]);
        }
}

__global__ void ws_sentinel(float* __restrict__ out, int n, float code) {
    int i = blockIdx.x * blockDim.x + threadIdx.x;
    if (i < n) out[i] = (i == 0) ? code : 0.0f;
}

// ---------------------------------------------------------------------------
extern "C" void kernel_launch(void* const* d_in, const int* in_sizes, int n_in,
                              void* d_out, int out_size, void* d_ws, size_t ws_size,
                              hipStream_t stream) {
    const float* q    = (const float*)d_in[0];
    const float* k    = (const float*)d_in[1];
    const float* v    = (const float*)d_in[2];
    const int*   mask = (const int*)d_in[3];
    const float* wq   = (const float*)d_in[4];
    const float* wk   = (const float*)d_in[5];
    const float* wv   = (const float*)d_in[6];
    const float* wo   = (const float*)d_in[7];
    float* out = (float*)d_out;

    if (ws_size < (size_t)33554432) {
        float code = 100.0f + (float)(ws_size >> 20);
        ws_sentinel<<<(out_size + 255) / 256, 256, 0, stream>>>(out, out_size, code);
        return;
    }

    ushort* ws = (ushort*)d_ws;
    ushort* Qb = ws;                       // [bh][s][dk] bf16 (scaled QSCALE); later: wo bf16
    ushort* Kb = ws + 4194304;             // [bh][s][dk]
    ushort* Vb = ws + 8388608;             // [bh][dk][s]  (transposed)
    ushort* Cb = ws + 12582912;            // first: wq/wk/wv bf16; then context [b,s,d] bf16

    dim3 blk(256, 1, 1);
    cvt_w<<<dim3(512, 3), blk, 0, stream>>>(wq, wk, wv, Cb);
    gemm_nt<0, 0><<<dim3(32, 8, 3), blk, 0, stream>>>(
        q, k, v, Cb, Cb + 1048576, Cb + 2097152, Qb, Kb, Vb);
    attn_fwd<<<dim3(512, 1, 1), dim3(512, 1, 1), 0, stream>>>(Qb, Kb, Vb, mask, Cb);
    cvt_w<<<dim3(512, 1), blk, 0, stream>>>(wo, wo, wo, Qb);
    gemm_nt<1, 1><<<dim3(32, 8, 1), blk, 0, stream>>>(
        Cb, Cb, Cb, Qb, Qb, Qb, out, out, out);
}